// Round 4
// baseline (474.755 us; speedup 1.0000x reference)
//
#include <hip/hip_runtime.h>

typedef unsigned short u16;
typedef short short8 __attribute__((ext_vector_type(8)));
typedef float f32x4 __attribute__((ext_vector_type(4)));

#define AS1C const __attribute__((address_space(1))) void*
#define AS3P __attribute__((address_space(3))) void*

// ---------- bf16 helpers ----------
__device__ __forceinline__ u16 f2b(float f) {
  unsigned u = __float_as_uint(f);
  return (u16)((u + 0x7fffu + ((u >> 16) & 1u)) >> 16);   // RNE
}
__device__ __forceinline__ float b2f(u16 h) {
  return __uint_as_float((unsigned)h << 16);
}

// ---------- problem constants ----------
#define BB 8
#define SS 4096
#define DD 256
#define NWIN 8
#define WIN 512
#define NH 2
#define KD 256
#define DFF 1024
#define MTOK (BB*SS)          // 32768 tokens

// ---------- workspace offsets (bytes) ----------
#define OFF_WQKVT  ((size_t)0)           // bf16 [1536][256]
#define OFF_WOT    ((size_t)786432)      // bf16 [256][512]
#define OFF_W1T    ((size_t)1048576)     // bf16 [1024][256]
#define OFF_W2T    ((size_t)1572864)     // bf16 [256][1024]
#define OFF_BQKV   ((size_t)2097152)     // f32  [1536]
#define OFF_XB     ((size_t)2103296)     // bf16 [32768][256]
#define OFF_QKV    ((size_t)18880512)    // bf16 [32768][1536]
#define OFF_Y      ((size_t)18880512)    // f32  [32768][256]   (alias; QKV dead when written)
#define OFF_YB     ((size_t)52434944)    // bf16 [32768][256]
#define OFF_HB     ((size_t)69212160)    // bf16 [32768][1024]
#define OFF_VT     ((size_t)119543808)   // bf16 [128][256][512]
#define OFF_CTX    ((size_t)153098240)   // bf16 [32768][512]
#define OFF_S      ((size_t)186652672)   // bf16 [128][512][512] (softmaxed P)

// ---------------------------------------------------------------------------
__global__ __launch_bounds__(256) void cast_x_kernel(const float* __restrict__ x,
                                                     u16* __restrict__ xb) {
  size_t i = ((size_t)blockIdx.x * 256 + threadIdx.x) * 4;
  float4 v = *(const float4*)(x + i);
  ushort4 o;
  o.x = f2b(v.x); o.y = f2b(v.y); o.z = f2b(v.z); o.w = f2b(v.w);
  *(ushort4*)(xb + i) = o;
}

// ---------------------------------------------------------------------------
__global__ __launch_bounds__(256) void prep_w_kernel(
    const float* __restrict__ Wq, const float* __restrict__ Wk, const float* __restrict__ Wv,
    const float* __restrict__ Wo, const float* __restrict__ W1, const float* __restrict__ W2,
    const float* __restrict__ bq, const float* __restrict__ bk, const float* __restrict__ bv,
    u16* __restrict__ wqkvt, u16* __restrict__ wot, u16* __restrict__ w1t,
    u16* __restrict__ w2t, float* __restrict__ bqkv)
{
  for (int i = blockIdx.x * 256 + threadIdx.x; i < 1050112; i += 1024 * 256) {
    if (i < 393216) {                       // WQKVT [1536][256]
      int n = i >> 8, d = i & 255;
      const float* W = (n < 512) ? Wq : (n < 1024) ? Wk : Wv;
      int nn = n & 511;
      wqkvt[i] = f2b(W[d * 512 + nn]);
    } else if (i < 524288) {                // WOT [256][512]
      int j = i - 393216;
      int dout = j >> 9, hk = j & 511;
      wot[j] = f2b(Wo[hk * 256 + dout]);
    } else if (i < 786432) {                // W1T [1024][256]
      int j = i - 524288;
      int f = j >> 8, d = j & 255;
      w1t[j] = f2b(W1[d * 1024 + f]);
    } else if (i < 1048576) {               // W2T [256][1024]
      int j = i - 786432;
      int d = j >> 10, f = j & 1023;
      w2t[j] = f2b(W2[f * 256 + d]);
    } else {                                // bias concat [1536]
      int n = i - 1048576;
      bqkv[n] = (n < 512) ? bq[n] : (n < 1024) ? bk[n - 512] : bv[n - 1024];
    }
  }
}

// ---------------------------------------------------------------------------
// GEMM: C = A[M,K] * BT[N,K]^T + bias (bf16 in, bf16/f32 out), opt relu.
// 128x128 tile, BK=64 single-buffer (half the vmcnt drains of BK=32).
// LDS row = 128 B -> XOR chunk swizzle p = c ^ (row&7) to avoid 16-way
// bank conflicts; swizzle applied on the global SOURCE side so the LDS
// destination stays lane-contiguous (global_load_lds requirement).
__global__ __launch_bounds__(256) void gemm_bt(
    const u16* __restrict__ A, const u16* __restrict__ BT,
    const float* __restrict__ bias, float* __restrict__ Cf, u16* __restrict__ Cb,
    int M, int N, int K, int relu)
{
  __shared__ __align__(16) u16 As[128 * 64];
  __shared__ __align__(16) u16 Bs[128 * 64];
  const int tid = threadIdx.x, lane = tid & 63, wid = tid >> 6;
  const int ln = lane & 15, quad = lane >> 4;
  const int nb = N >> 7;
  const long bm = (long)(blockIdx.x / nb) << 7;
  const long bn = (long)(blockIdx.x % nb) << 7;
  const int wm = (wid >> 1) << 6, wn = (wid & 1) << 6;
  const u16* Ab = A + (size_t)bm * K;
  const u16* Bb = BT + (size_t)bn * K;

  f32x4 acc[4][4];
#pragma unroll
  for (int i = 0; i < 4; i++)
#pragma unroll
    for (int j = 0; j < 4; j++) acc[i][j] = (f32x4){0.f, 0.f, 0.f, 0.f};

  for (int kt = 0; kt < K; kt += 64) {
#pragma unroll
    for (int p = 0; p < 4; p++) {
      const int s = p * 256 + tid;          // slot: 1024 x 16B per array
      const int row = s >> 3, pc = s & 7;
      const int c = pc ^ (row & 7);         // source chunk for this slot
      __builtin_amdgcn_global_load_lds(
          (AS1C)(Ab + (size_t)row * K + kt + c * 8), (AS3P)(As + s * 8), 16, 0, 0);
      __builtin_amdgcn_global_load_lds(
          (AS1C)(Bb + (size_t)row * K + kt + c * 8), (AS3P)(Bs + s * 8), 16, 0, 0);
    }
    __syncthreads();
#pragma unroll
    for (int ks = 0; ks < 64; ks += 32) {
      short8 a[4], b[4];
#pragma unroll
      for (int i = 0; i < 4; i++) {
        const int r = wm + i * 16 + ln;
        const int p = ((ks >> 3) + quad) ^ (r & 7);
        a[i] = *(const short8*)(As + r * 64 + p * 8);
      }
#pragma unroll
      for (int j = 0; j < 4; j++) {
        const int r = wn + j * 16 + ln;
        const int p = ((ks >> 3) + quad) ^ (r & 7);
        b[j] = *(const short8*)(Bs + r * 64 + p * 8);
      }
#pragma unroll
      for (int i = 0; i < 4; i++)
#pragma unroll
        for (int j = 0; j < 4; j++)
          acc[i][j] = __builtin_amdgcn_mfma_f32_16x16x32_bf16(b[j], a[i], acc[i][j], 0, 0, 0);
    }
    __syncthreads();
  }

  // epilogue: swapped operands -> lane holds C[m][n0..n0+3]
#pragma unroll
  for (int i = 0; i < 4; i++) {
    const long m = bm + wm + i * 16 + ln;
#pragma unroll
    for (int j = 0; j < 4; j++) {
      const long n0 = bn + wn + j * 16 + quad * 4;
      f32x4 v = acc[i][j];
      if (bias) {
        const float4 b4 = *(const float4*)(bias + n0);
        v[0] += b4.x; v[1] += b4.y; v[2] += b4.z; v[3] += b4.w;
      }
      if (relu) {
#pragma unroll
        for (int r = 0; r < 4; r++) v[r] = fmaxf(v[r], 0.f);
      }
      const size_t off = (size_t)m * N + n0;
      if (Cf) {
        float4 o4; o4.x = v[0]; o4.y = v[1]; o4.z = v[2]; o4.w = v[3];
        *(float4*)(Cf + off) = o4;
      }
      if (Cb) {
        ushort4 ob;
        ob.x = f2b(v[0]); ob.y = f2b(v[1]); ob.z = f2b(v[2]); ob.w = f2b(v[3]);
        *(ushort4*)(Cb + off) = ob;
      }
    }
  }
}

// ---------------------------------------------------------------------------
// QK^T with FUSED softmax. One block = one (b,w,h) batch x 64 Q-rows x all
// 512 keys. 512 threads = 8 waves, wave w covers keys [w*64, w*64+64).
// Swapped MFMA: lane holds S[m][n0..n0+3]. Cross-wave max/sum via LDS.
__global__ __launch_bounds__(512) void bgemm_qk(const u16* __restrict__ qkv,
                                                u16* __restrict__ S)
{
  __shared__ __align__(16) u16 As[64 * 32];
  __shared__ __align__(16) u16 Bs[512 * 32];
  __shared__ float red1[8][64], red2[8][64];
  const int tid = threadIdx.x, lane = tid & 63, wid = tid >> 6;
  const int ln = lane & 15, quad = lane >> 4;
  const int bat = blockIdx.x >> 3, mt = blockIdx.x & 7;
  const int bw = bat >> 1, h = bat & 1;
  const u16* Qb = qkv + (size_t)bw * 786432 + (size_t)h * 256 + (size_t)(mt * 64) * 1536;
  const u16* Kb = qkv + (size_t)bw * 786432 + 512 + (size_t)h * 256;
  u16* Sb = S + (size_t)bat * 262144 + (size_t)(mt * 64) * 512;
  const int wn = wid * 64;

  f32x4 acc[4][4];
#pragma unroll
  for (int i = 0; i < 4; i++)
#pragma unroll
    for (int j = 0; j < 4; j++) acc[i][j] = (f32x4){0.f, 0.f, 0.f, 0.f};

  for (int kt = 0; kt < 256; kt += 32) {
    if (tid < 256) {                        // Q tile: 64x32 = 256 slots
      const int row = tid >> 2, c = tid & 3;
      __builtin_amdgcn_global_load_lds(
          (AS1C)(Qb + (size_t)row * 1536 + kt + c * 8), (AS3P)(As + tid * 8), 16, 0, 0);
    }
#pragma unroll
    for (int p = 0; p < 4; p++) {           // K tile: 512x32 = 2048 slots
      const int s = p * 512 + tid;
      const int row = s >> 2, c = s & 3;
      __builtin_amdgcn_global_load_lds(
          (AS1C)(Kb + (size_t)row * 1536 + kt + c * 8), (AS3P)(Bs + s * 8), 16, 0, 0);
    }
    __syncthreads();
    short8 a[4], b[4];
#pragma unroll
    for (int i = 0; i < 4; i++) a[i] = *(const short8*)(As + (i * 16 + ln) * 32 + quad * 8);
#pragma unroll
    for (int j = 0; j < 4; j++) b[j] = *(const short8*)(Bs + (wn + j * 16 + ln) * 32 + quad * 8);
#pragma unroll
    for (int i = 0; i < 4; i++)
#pragma unroll
      for (int j = 0; j < 4; j++)
        acc[i][j] = __builtin_amdgcn_mfma_f32_16x16x32_bf16(b[j], a[i], acc[i][j], 0, 0, 0);
    __syncthreads();
  }

  // ---- fused softmax over the full 512-wide row ----
  // pass 1: row max
  float rowmax[4];
#pragma unroll
  for (int i = 0; i < 4; i++) {
    float m = -1e30f;
#pragma unroll
    for (int j = 0; j < 4; j++)
#pragma unroll
      for (int r = 0; r < 4; r++) m = fmaxf(m, acc[i][j][r]);
    m = fmaxf(m, __shfl_xor(m, 16));
    m = fmaxf(m, __shfl_xor(m, 32));
    if (quad == 0) red1[wid][i * 16 + ln] = m;
    rowmax[i] = m;
  }
  __syncthreads();
#pragma unroll
  for (int i = 0; i < 4; i++) {
    float m = -1e30f;
#pragma unroll
    for (int w = 0; w < 8; w++) m = fmaxf(m, red1[w][i * 16 + ln]);
    rowmax[i] = m;
  }
  // pass 2: exp + row sum
  float rowsum[4];
#pragma unroll
  for (int i = 0; i < 4; i++) {
    float s = 0.f;
#pragma unroll
    for (int j = 0; j < 4; j++)
#pragma unroll
      for (int r = 0; r < 4; r++) {
        const float e = __expf((acc[i][j][r] - rowmax[i]) * 0.0625f); // 1/sqrt(256)
        acc[i][j][r] = e; s += e;
      }
    s += __shfl_xor(s, 16);
    s += __shfl_xor(s, 32);
    if (quad == 0) red2[wid][i * 16 + ln] = s;
  }
  __syncthreads();
#pragma unroll
  for (int i = 0; i < 4; i++) {
    float s = 0.f;
#pragma unroll
    for (int w = 0; w < 8; w++) s += red2[w][i * 16 + ln];
    rowsum[i] = 1.f / s;
  }
  // write P (bf16)
#pragma unroll
  for (int i = 0; i < 4; i++) {
    const size_t roff = (size_t)(i * 16 + ln) * 512;
#pragma unroll
    for (int j = 0; j < 4; j++) {
      const int n0 = wn + j * 16 + quad * 4;
      ushort4 ob;
      ob.x = f2b(acc[i][j][0] * rowsum[i]);
      ob.y = f2b(acc[i][j][1] * rowsum[i]);
      ob.z = f2b(acc[i][j][2] * rowsum[i]);
      ob.w = f2b(acc[i][j][3] * rowsum[i]);
      *(ushort4*)(Sb + roff + n0) = ob;
    }
  }
}

// ---------------------------------------------------------------------------
// batched GEMM (P·V) over 128 blocks: C = A * B^T, bf16. dbuf BK=32 (r3 form).
#define GSTAGE(Sptr, Gptr, ld)                                                     \
  __builtin_amdgcn_global_load_lds(                                                \
      (AS1C)((Gptr) + (size_t)rr * (ld) + kt2 + skk),                              \
      (AS3P)((Sptr) + (size_t)(i * 64 + wid * 16) * 32), 16, 0, 0)

__global__ __launch_bounds__(256) void bgemm(
    const u16* __restrict__ A, long sAbw, long sAh, int lda,
    const u16* __restrict__ B, long sBbw, long sBh, int ldb,
    u16* __restrict__ C, long sCbw, long sCh, int ldc,
    int K, int Ntiles)
{
  __shared__ __align__(16) u16 As[2][128 * 32];
  __shared__ __align__(16) u16 Bs[2][128 * 32];
  const int tid = threadIdx.x, lane = tid & 63, wid = tid >> 6;
  const int ln = lane & 15, quad = lane >> 4;
  const int per = 4 * Ntiles;
  const int blk = blockIdx.x / per;
  const int rem = blockIdx.x % per;
  const int mt = rem / Ntiles, nt = rem % Ntiles;
  const int bw = blk >> 1, h = blk & 1;
  const u16* Ab = A + (size_t)bw * sAbw + (size_t)h * sAh + (size_t)mt * 128 * lda;
  const u16* Bp = B + (size_t)bw * sBbw + (size_t)h * sBh + (size_t)nt * 128 * ldb;
  u16*       Cp = C + (size_t)bw * sCbw + (size_t)h * sCh + (size_t)mt * 128 * ldc + nt * 128;
  const int srow = lane >> 2;
  const int skk  = (lane & 3) << 3;
  const int wm = (wid >> 1) << 6, wn = (wid & 1) << 6;

  f32x4 acc[4][4];
#pragma unroll
  for (int i = 0; i < 4; i++)
#pragma unroll
    for (int j = 0; j < 4; j++) acc[i][j] = (f32x4){0.f, 0.f, 0.f, 0.f};

  {
    const int kt2 = 0;
#pragma unroll
    for (int i = 0; i < 2; i++) {
      const int rr = i * 64 + wid * 16 + srow;
      GSTAGE(As[0], Ab, lda);
      GSTAGE(Bs[0], Bp, ldb);
    }
  }
  int cur = 0;
  for (int kt = 0; kt < K; kt += 32, cur ^= 1) {
    __syncthreads();
    if (kt + 32 < K) {
      const int kt2 = kt + 32;
#pragma unroll
      for (int i = 0; i < 2; i++) {
        const int rr = i * 64 + wid * 16 + srow;
        GSTAGE(As[cur ^ 1], Ab, lda);
        GSTAGE(Bs[cur ^ 1], Bp, ldb);
      }
    }
    short8 a[4], b[4];
#pragma unroll
    for (int i = 0; i < 4; i++) a[i] = *(const short8*)(As[cur] + (wm + i * 16 + ln) * 32 + quad * 8);
#pragma unroll
    for (int j = 0; j < 4; j++) b[j] = *(const short8*)(Bs[cur] + (wn + j * 16 + ln) * 32 + quad * 8);
#pragma unroll
    for (int i = 0; i < 4; i++)
#pragma unroll
      for (int j = 0; j < 4; j++)
        acc[i][j] = __builtin_amdgcn_mfma_f32_16x16x32_bf16(b[j], a[i], acc[i][j], 0, 0, 0);
  }

#pragma unroll
  for (int i = 0; i < 4; i++) {
    const int m = wm + i * 16 + ln;
#pragma unroll
    for (int j = 0; j < 4; j++) {
      const int n0 = wn + j * 16 + quad * 4;
      const f32x4 v = acc[i][j];
      ushort4 ob;
      ob.x = f2b(v[0]); ob.y = f2b(v[1]); ob.z = f2b(v[2]); ob.w = f2b(v[3]);
      *(ushort4*)(Cp + (size_t)m * ldc + n0) = ob;
    }
  }
}

// ---------------------------------------------------------------------------
// GEMM (N=256) with FUSED residual + LayerNorm epilogue.
// Block = 64 rows x 256 cols (4 waves side-by-side in N) so every row is
// complete inside the block. A[M,K] bf16, BT[256,K] bf16.
// yout (f32, optional), ybout (bf16, optional).
__global__ __launch_bounds__(256) void gemm_ln(
    const u16* __restrict__ A, const u16* __restrict__ BT,
    const float* __restrict__ bias, const float* __restrict__ resid,
    const float* __restrict__ g, const float* __restrict__ beta,
    float* __restrict__ yout, u16* __restrict__ ybout, int K)
{
  __shared__ __align__(16) u16 As[64 * 32];
  __shared__ __align__(16) u16 Bs[256 * 32];
  __shared__ float redS[4][64], redQ[4][64];
  const int tid = threadIdx.x, lane = tid & 63, wid = tid >> 6;
  const int ln = lane & 15, quad = lane >> 4;
  const long bm = (long)blockIdx.x * 64;
  const int wn = wid * 64;
  const u16* Ab = A + (size_t)bm * K;

  f32x4 acc[4][4];
#pragma unroll
  for (int i = 0; i < 4; i++)
#pragma unroll
    for (int j = 0; j < 4; j++) acc[i][j] = (f32x4){0.f, 0.f, 0.f, 0.f};

  for (int kt = 0; kt < K; kt += 32) {
    {                                       // A: 64x32 = 256 slots, 1/thread
      const int row = tid >> 2, c = tid & 3;
      __builtin_amdgcn_global_load_lds(
          (AS1C)(Ab + (size_t)row * K + kt + c * 8), (AS3P)(As + tid * 8), 16, 0, 0);
    }
#pragma unroll
    for (int p = 0; p < 4; p++) {           // B: 256x32 = 1024 slots
      const int s = p * 256 + tid;
      const int row = s >> 2, c = s & 3;
      __builtin_amdgcn_global_load_lds(
          (AS1C)(BT + (size_t)row * K + kt + c * 8), (AS3P)(Bs + s * 8), 16, 0, 0);
    }
    __syncthreads();
    short8 a[4], b[4];
#pragma unroll
    for (int i = 0; i < 4; i++) a[i] = *(const short8*)(As + (i * 16 + ln) * 32 + quad * 8);
#pragma unroll
    for (int j = 0; j < 4; j++) b[j] = *(const short8*)(Bs + (wn + j * 16 + ln) * 32 + quad * 8);
#pragma unroll
    for (int i = 0; i < 4; i++)
#pragma unroll
      for (int j = 0; j < 4; j++)
        acc[i][j] = __builtin_amdgcn_mfma_f32_16x16x32_bf16(b[j], a[i], acc[i][j], 0, 0, 0);
    __syncthreads();
  }

  // ---- epilogue: v = acc + bias + resid; LayerNorm over the 256-row ----
#pragma unroll
  for (int i = 0; i < 4; i++) {
    const long gm = bm + i * 16 + ln;
    float s = 0.f, q = 0.f;
#pragma unroll
    for (int j = 0; j < 4; j++) {
      const int n0 = wn + j * 16 + quad * 4;
      const float4 b4 = *(const float4*)(bias + n0);
      const float4 r4 = *(const float4*)(resid + (size_t)gm * 256 + n0);
      acc[i][j][0] += b4.x + r4.x;
      acc[i][j][1] += b4.y + r4.y;
      acc[i][j][2] += b4.z + r4.z;
      acc[i][j][3] += b4.w + r4.w;
#pragma unroll
      for (int r = 0; r < 4; r++) { s += acc[i][j][r]; q += acc[i][j][r] * acc[i][j][r]; }
    }
    s += __shfl_xor(s, 16); s += __shfl_xor(s, 32);
    q += __shfl_xor(q, 16); q += __shfl_xor(q, 32);
    if (quad == 0) { redS[wid][i * 16 + ln] = s; redQ[wid][i * 16 + ln] = q; }
  }
  __syncthreads();
#pragma unroll
  for (int i = 0; i < 4; i++) {
    const long gm = bm + i * 16 + ln;
    float s = 0.f, q = 0.f;
#pragma unroll
    for (int w = 0; w < 4; w++) { s += redS[w][i * 16 + ln]; q += redQ[w][i * 16 + ln]; }
    const float mu = s * (1.f / 256.f);
    const float inv = rsqrtf(q * (1.f / 256.f) - mu * mu + 1e-3f);
#pragma unroll
    for (int j = 0; j < 4; j++) {
      const int n0 = wn + j * 16 + quad * 4;
      const float4 gg = *(const float4*)(g + n0);
      const float4 bb = *(const float4*)(beta + n0);
      float o0 = (acc[i][j][0] - mu) * inv * gg.x + bb.x;
      float o1 = (acc[i][j][1] - mu) * inv * gg.y + bb.y;
      float o2 = (acc[i][j][2] - mu) * inv * gg.z + bb.z;
      float o3 = (acc[i][j][3] - mu) * inv * gg.w + bb.w;
      const size_t off = (size_t)gm * 256 + n0;
      if (yout) {
        float4 o4; o4.x = o0; o4.y = o1; o4.z = o2; o4.w = o3;
        *(float4*)(yout + off) = o4;
      }
      if (ybout) {
        ushort4 ob;
        ob.x = f2b(o0); ob.y = f2b(o1); ob.z = f2b(o2); ob.w = f2b(o3);
        *(ushort4*)(ybout + off) = ob;
      }
    }
  }
}

// ---------------------------------------------------------------------------
__global__ __launch_bounds__(256) void transpose_v(const u16* __restrict__ qkv,
                                                   u16* __restrict__ vt)
{
  __shared__ u16 tile[64][72];
  const int bid = blockIdx.x;                 // 128 * 8 * 4
  const int kt4 = bid & 3, tt = (bid >> 2) & 7, blk = bid >> 5;
  const int bw = blk >> 1, h = blk & 1;
  const int lk = threadIdx.x & 63, l0 = threadIdx.x >> 6;
#pragma unroll
  for (int i = 0; i < 16; i++) {
    const int lt = l0 + i * 4;
    tile[lt][lk] = qkv[(size_t)(bw * 512 + tt * 64 + lt) * 1536 + 1024 + h * 256 + kt4 * 64 + lk];
  }
  __syncthreads();
#pragma unroll
  for (int i = 0; i < 16; i++) {
    const int kk = l0 + i * 4;
    vt[((size_t)blk * 256 + kt4 * 64 + kk) * 512 + tt * 64 + lk] = tile[lk][kk];
  }
}

// ---------------------------------------------------------------------------
extern "C" void kernel_launch(void* const* d_in, const int* in_sizes, int n_in,
                              void* d_out, int out_size, void* d_ws, size_t ws_size,
                              hipStream_t stream) {
  (void)in_sizes; (void)n_in; (void)out_size; (void)ws_size;
  const float* x    = (const float*)d_in[0];
  const float* Wq   = (const float*)d_in[1];
  const float* bq   = (const float*)d_in[2];
  const float* Wk   = (const float*)d_in[3];
  const float* bk   = (const float*)d_in[4];
  const float* Wv   = (const float*)d_in[5];
  const float* bv   = (const float*)d_in[6];
  const float* Wo   = (const float*)d_in[7];
  const float* bo   = (const float*)d_in[8];
  const float* ln1g = (const float*)d_in[9];
  const float* ln1b = (const float*)d_in[10];
  const float* W1   = (const float*)d_in[11];
  const float* b1   = (const float*)d_in[12];
  const float* W2   = (const float*)d_in[13];
  const float* b2   = (const float*)d_in[14];
  const float* ln2g = (const float*)d_in[15];
  const float* ln2b = (const float*)d_in[16];
  float* out = (float*)d_out;

  char* ws = (char*)d_ws;
  u16*   WQKVT = (u16*)(ws + OFF_WQKVT);
  u16*   WOT   = (u16*)(ws + OFF_WOT);
  u16*   W1T   = (u16*)(ws + OFF_W1T);
  u16*   W2T   = (u16*)(ws + OFF_W2T);
  float* BQKV  = (float*)(ws + OFF_BQKV);
  u16*   XB    = (u16*)(ws + OFF_XB);
  u16*   QKV   = (u16*)(ws + OFF_QKV);
  float* Y     = (float*)(ws + OFF_Y);
  u16*   YB    = (u16*)(ws + OFF_YB);
  u16*   HB    = (u16*)(ws + OFF_HB);
  u16*   VT    = (u16*)(ws + OFF_VT);
  u16*   CTX   = (u16*)(ws + OFF_CTX);
  u16*   S     = (u16*)(ws + OFF_S);

  cast_x_kernel<<<8192, 256, 0, stream>>>(x, XB);
  prep_w_kernel<<<1024, 256, 0, stream>>>(Wq, Wk, Wv, Wo, W1, W2, bq, bk, bv,
                                          WQKVT, WOT, W1T, W2T, BQKV);
  // QKV projection: [32768,256] x [256,1536], BK=64
  gemm_bt<<<3072, 256, 0, stream>>>(XB, WQKVT, BQKV, nullptr, QKV,
                                    MTOK, 1536, 256, 0);
  transpose_v<<<4096, 256, 0, stream>>>(QKV, VT);
  // P = softmax(Q K^T / 16), fused: 128 batches x 8 m-tiles
  bgemm_qk<<<1024, 512, 0, stream>>>(QKV, S);
  // CTX = P V batched: M=512,N=256,K=512
  bgemm<<<1024, 256, 0, stream>>>(S,   524288, 262144, 512,
                                  VT,  262144, 131072, 512,
                                  CTX, 262144, 256, 512,
                                  512, 2);
  // attn-out projection + residual(x) + LN1 -> Y (f32) + YB (bf16)
  gemm_ln<<<512, 256, 0, stream>>>(CTX, WOT, bo, x, ln1g, ln1b, Y, YB, 512);
  // FF1 + ReLU: [32768,256] x [256,1024], BK=64
  gemm_bt<<<2048, 256, 0, stream>>>(YB, W1T, b1, nullptr, HB,
                                    MTOK, 1024, 256, 1);
  // FF2 + residual(Y) + LN2 -> out (f32)
  gemm_ln<<<512, 256, 0, stream>>>(HB, W2T, b2, Y, ln2g, ln2b, out, nullptr, 1024);
}

// Round 5
// 415.397 us; speedup vs baseline: 1.1429x; 1.1429x over previous
//
#include <hip/hip_runtime.h>

typedef unsigned short u16;
typedef short short8 __attribute__((ext_vector_type(8)));
typedef float f32x4 __attribute__((ext_vector_type(4)));

#define AS1C const __attribute__((address_space(1))) void*
#define AS3P __attribute__((address_space(3))) void*

// ---------- bf16 helpers ----------
__device__ __forceinline__ u16 f2b(float f) {
  unsigned u = __float_as_uint(f);
  return (u16)((u + 0x7fffu + ((u >> 16) & 1u)) >> 16);   // RNE
}
__device__ __forceinline__ float b2f(u16 h) {
  return __uint_as_float((unsigned)h << 16);
}

// ---------- problem constants ----------
#define BB 8
#define SS 4096
#define DD 256
#define NWIN 8
#define WIN 512
#define NH 2
#define KD 256
#define DFF 1024
#define MTOK (BB*SS)          // 32768 tokens

// ---------- workspace offsets (bytes) ----------
#define OFF_WQKVT  ((size_t)0)           // bf16 [1536][256]
#define OFF_WOT    ((size_t)786432)      // bf16 [256][512]
#define OFF_W1T    ((size_t)1048576)     // bf16 [1024][256]
#define OFF_W2T    ((size_t)1572864)     // bf16 [256][1024]
#define OFF_BQKV   ((size_t)2097152)     // f32  [1536]
#define OFF_XB     ((size_t)2103296)     // bf16 [32768][256]
#define OFF_QKV    ((size_t)18880512)    // bf16 [32768][1536]
#define OFF_Y      ((size_t)18880512)    // f32  [32768][256]   (alias; QKV dead when written)
#define OFF_YB     ((size_t)52434944)    // bf16 [32768][256]
#define OFF_HB     ((size_t)69212160)    // bf16 [32768][1024]
#define OFF_VT     ((size_t)119543808)   // bf16 [128][256][512]
#define OFF_CTX    ((size_t)153098240)   // bf16 [32768][512]
#define OFF_S      ((size_t)186652672)   // bf16 [128][512][512] (softmaxed P)

// ---------------------------------------------------------------------------
__global__ __launch_bounds__(256) void cast_x_kernel(const float* __restrict__ x,
                                                     u16* __restrict__ xb) {
  size_t i = ((size_t)blockIdx.x * 256 + threadIdx.x) * 4;
  float4 v = *(const float4*)(x + i);
  ushort4 o;
  o.x = f2b(v.x); o.y = f2b(v.y); o.z = f2b(v.z); o.w = f2b(v.w);
  *(ushort4*)(xb + i) = o;
}

// ---------------------------------------------------------------------------
__global__ __launch_bounds__(256) void prep_w_kernel(
    const float* __restrict__ Wq, const float* __restrict__ Wk, const float* __restrict__ Wv,
    const float* __restrict__ Wo, const float* __restrict__ W1, const float* __restrict__ W2,
    const float* __restrict__ bq, const float* __restrict__ bk, const float* __restrict__ bv,
    u16* __restrict__ wqkvt, u16* __restrict__ wot, u16* __restrict__ w1t,
    u16* __restrict__ w2t, float* __restrict__ bqkv)
{
  for (int i = blockIdx.x * 256 + threadIdx.x; i < 1050112; i += 1024 * 256) {
    if (i < 393216) {                       // WQKVT [1536][256]
      int n = i >> 8, d = i & 255;
      const float* W = (n < 512) ? Wq : (n < 1024) ? Wk : Wv;
      int nn = n & 511;
      wqkvt[i] = f2b(W[d * 512 + nn]);
    } else if (i < 524288) {                // WOT [256][512]
      int j = i - 393216;
      int dout = j >> 9, hk = j & 511;
      wot[j] = f2b(Wo[hk * 256 + dout]);
    } else if (i < 786432) {                // W1T [1024][256]
      int j = i - 524288;
      int f = j >> 8, d = j & 255;
      w1t[j] = f2b(W1[d * 1024 + f]);
    } else if (i < 1048576) {               // W2T [256][1024]
      int j = i - 786432;
      int d = j >> 10, f = j & 1023;
      w2t[j] = f2b(W2[f * 256 + d]);
    } else {                                // bias concat [1536]
      int n = i - 1048576;
      bqkv[n] = (n < 512) ? bq[n] : (n < 1024) ? bk[n - 512] : bv[n - 1024];
    }
  }
}

// ---------------------------------------------------------------------------
// GEMM: C = A[M,K] * BT[N,K]^T + bias (bf16 in, bf16/f32 out), opt relu.
// 128x128 tile, BK=64 single-buffer. XOR chunk swizzle on global source side.
// XCD swizzle: bm = bid & 255 so all n-blocks sharing an A-panel have the
// same bid%8 -> same XCD -> A-panel served from that XCD's L2.
__global__ __launch_bounds__(256) void gemm_bt(
    const u16* __restrict__ A, const u16* __restrict__ BT,
    const float* __restrict__ bias, float* __restrict__ Cf, u16* __restrict__ Cb,
    int M, int N, int K, int relu)
{
  __shared__ __align__(16) u16 As[128 * 64];
  __shared__ __align__(16) u16 Bs[128 * 64];
  const int tid = threadIdx.x, lane = tid & 63, wid = tid >> 6;
  const int ln = lane & 15, quad = lane >> 4;
  const long bm = (long)(blockIdx.x & 255) << 7;     // M=32768 -> 256 m-tiles
  const long bn = (long)(blockIdx.x >> 8) << 7;
  const int wm = (wid >> 1) << 6, wn = (wid & 1) << 6;
  const u16* Ab = A + (size_t)bm * K;
  const u16* Bb = BT + (size_t)bn * K;

  f32x4 acc[4][4];
#pragma unroll
  for (int i = 0; i < 4; i++)
#pragma unroll
    for (int j = 0; j < 4; j++) acc[i][j] = (f32x4){0.f, 0.f, 0.f, 0.f};

  for (int kt = 0; kt < K; kt += 64) {
#pragma unroll
    for (int p = 0; p < 4; p++) {
      const int s = p * 256 + tid;          // slot: 1024 x 16B per array
      const int row = s >> 3, pc = s & 7;
      const int c = pc ^ (row & 7);         // source chunk for this slot
      __builtin_amdgcn_global_load_lds(
          (AS1C)(Ab + (size_t)row * K + kt + c * 8), (AS3P)(As + s * 8), 16, 0, 0);
      __builtin_amdgcn_global_load_lds(
          (AS1C)(Bb + (size_t)row * K + kt + c * 8), (AS3P)(Bs + s * 8), 16, 0, 0);
    }
    __syncthreads();
#pragma unroll
    for (int ks = 0; ks < 64; ks += 32) {
      short8 a[4], b[4];
#pragma unroll
      for (int i = 0; i < 4; i++) {
        const int r = wm + i * 16 + ln;
        const int p = ((ks >> 3) + quad) ^ (r & 7);
        a[i] = *(const short8*)(As + r * 64 + p * 8);
      }
#pragma unroll
      for (int j = 0; j < 4; j++) {
        const int r = wn + j * 16 + ln;
        const int p = ((ks >> 3) + quad) ^ (r & 7);
        b[j] = *(const short8*)(Bs + r * 64 + p * 8);
      }
#pragma unroll
      for (int i = 0; i < 4; i++)
#pragma unroll
        for (int j = 0; j < 4; j++)
          acc[i][j] = __builtin_amdgcn_mfma_f32_16x16x32_bf16(b[j], a[i], acc[i][j], 0, 0, 0);
    }
    __syncthreads();
  }

  // epilogue: swapped operands -> lane holds C[m][n0..n0+3]
#pragma unroll
  for (int i = 0; i < 4; i++) {
    const long m = bm + wm + i * 16 + ln;
#pragma unroll
    for (int j = 0; j < 4; j++) {
      const long n0 = bn + wn + j * 16 + quad * 4;
      f32x4 v = acc[i][j];
      if (bias) {
        const float4 b4 = *(const float4*)(bias + n0);
        v[0] += b4.x; v[1] += b4.y; v[2] += b4.z; v[3] += b4.w;
      }
      if (relu) {
#pragma unroll
        for (int r = 0; r < 4; r++) v[r] = fmaxf(v[r], 0.f);
      }
      const size_t off = (size_t)m * N + n0;
      if (Cf) {
        float4 o4; o4.x = v[0]; o4.y = v[1]; o4.z = v[2]; o4.w = v[3];
        *(float4*)(Cf + off) = o4;
      }
      if (Cb) {
        ushort4 ob;
        ob.x = f2b(v[0]); ob.y = f2b(v[1]); ob.z = f2b(v[2]); ob.w = f2b(v[3]);
        *(ushort4*)(Cb + off) = ob;
      }
    }
  }
}

// ---------------------------------------------------------------------------
// QK^T with FUSED softmax. One block = one (b,w,h) batch x 64 Q-rows x all
// 512 keys. 512 threads = 8 waves, wave w covers keys [w*64, w*64+64).
// XCD swizzle: bat = bid & 127 so the 8 m-tile blocks of one batch share an
// XCD and the 262 KB K-tile is fetched once per XCD (16 batches x 262 KB
// ~= 4 MB = one XCD L2).
__global__ __launch_bounds__(512) void bgemm_qk(const u16* __restrict__ qkv,
                                                u16* __restrict__ S)
{
  __shared__ __align__(16) u16 As[64 * 32];
  __shared__ __align__(16) u16 Bs[512 * 32];
  __shared__ float red1[8][64], red2[8][64];
  const int tid = threadIdx.x, lane = tid & 63, wid = tid >> 6;
  const int ln = lane & 15, quad = lane >> 4;
  const int bat = blockIdx.x & 127, mt = blockIdx.x >> 7;
  const int bw = bat >> 1, h = bat & 1;
  const u16* Qb = qkv + (size_t)bw * 786432 + (size_t)h * 256 + (size_t)(mt * 64) * 1536;
  const u16* Kb = qkv + (size_t)bw * 786432 + 512 + (size_t)h * 256;
  u16* Sb = S + (size_t)bat * 262144 + (size_t)(mt * 64) * 512;
  const int wn = wid * 64;

  f32x4 acc[4][4];
#pragma unroll
  for (int i = 0; i < 4; i++)
#pragma unroll
    for (int j = 0; j < 4; j++) acc[i][j] = (f32x4){0.f, 0.f, 0.f, 0.f};

  for (int kt = 0; kt < 256; kt += 32) {
    if (tid < 256) {                        // Q tile: 64x32 = 256 slots
      const int row = tid >> 2, c = tid & 3;
      __builtin_amdgcn_global_load_lds(
          (AS1C)(Qb + (size_t)row * 1536 + kt + c * 8), (AS3P)(As + tid * 8), 16, 0, 0);
    }
#pragma unroll
    for (int p = 0; p < 4; p++) {           // K tile: 512x32 = 2048 slots
      const int s = p * 512 + tid;
      const int row = s >> 2, c = s & 3;
      __builtin_amdgcn_global_load_lds(
          (AS1C)(Kb + (size_t)row * 1536 + kt + c * 8), (AS3P)(Bs + s * 8), 16, 0, 0);
    }
    __syncthreads();
    short8 a[4], b[4];
#pragma unroll
    for (int i = 0; i < 4; i++) a[i] = *(const short8*)(As + (i * 16 + ln) * 32 + quad * 8);
#pragma unroll
    for (int j = 0; j < 4; j++) b[j] = *(const short8*)(Bs + (wn + j * 16 + ln) * 32 + quad * 8);
#pragma unroll
    for (int i = 0; i < 4; i++)
#pragma unroll
      for (int j = 0; j < 4; j++)
        acc[i][j] = __builtin_amdgcn_mfma_f32_16x16x32_bf16(b[j], a[i], acc[i][j], 0, 0, 0);
    __syncthreads();
  }

  // ---- fused softmax over the full 512-wide row ----
  float rowmax[4];
#pragma unroll
  for (int i = 0; i < 4; i++) {
    float m = -1e30f;
#pragma unroll
    for (int j = 0; j < 4; j++)
#pragma unroll
      for (int r = 0; r < 4; r++) m = fmaxf(m, acc[i][j][r]);
    m = fmaxf(m, __shfl_xor(m, 16));
    m = fmaxf(m, __shfl_xor(m, 32));
    if (quad == 0) red1[wid][i * 16 + ln] = m;
    rowmax[i] = m;
  }
  __syncthreads();
#pragma unroll
  for (int i = 0; i < 4; i++) {
    float m = -1e30f;
#pragma unroll
    for (int w = 0; w < 8; w++) m = fmaxf(m, red1[w][i * 16 + ln]);
    rowmax[i] = m;
  }
  float rowsum[4];
#pragma unroll
  for (int i = 0; i < 4; i++) {
    float s = 0.f;
#pragma unroll
    for (int j = 0; j < 4; j++)
#pragma unroll
      for (int r = 0; r < 4; r++) {
        const float e = __expf((acc[i][j][r] - rowmax[i]) * 0.0625f); // 1/sqrt(256)
        acc[i][j][r] = e; s += e;
      }
    s += __shfl_xor(s, 16);
    s += __shfl_xor(s, 32);
    if (quad == 0) red2[wid][i * 16 + ln] = s;
  }
  __syncthreads();
#pragma unroll
  for (int i = 0; i < 4; i++) {
    float s = 0.f;
#pragma unroll
    for (int w = 0; w < 8; w++) s += red2[w][i * 16 + ln];
    rowsum[i] = 1.f / s;
  }
#pragma unroll
  for (int i = 0; i < 4; i++) {
    const size_t roff = (size_t)(i * 16 + ln) * 512;
#pragma unroll
    for (int j = 0; j < 4; j++) {
      const int n0 = wn + j * 16 + quad * 4;
      ushort4 ob;
      ob.x = f2b(acc[i][j][0] * rowsum[i]);
      ob.y = f2b(acc[i][j][1] * rowsum[i]);
      ob.z = f2b(acc[i][j][2] * rowsum[i]);
      ob.w = f2b(acc[i][j][3] * rowsum[i]);
      *(ushort4*)(Sb + roff + n0) = ob;
    }
  }
}

// ---------------------------------------------------------------------------
// batched GEMM (P·V) over 128 blocks: C = A * B^T, bf16. dbuf BK=32.
// XCD swizzle: blk = bid & 127 -> tile-sharers co-reside on one XCD.
#define GSTAGE(Sptr, Gptr, ld)                                                     \
  __builtin_amdgcn_global_load_lds(                                                \
      (AS1C)((Gptr) + (size_t)rr * (ld) + kt2 + skk),                              \
      (AS3P)((Sptr) + (size_t)(i * 64 + wid * 16) * 32), 16, 0, 0)

__global__ __launch_bounds__(256) void bgemm(
    const u16* __restrict__ A, long sAbw, long sAh, int lda,
    const u16* __restrict__ B, long sBbw, long sBh, int ldb,
    u16* __restrict__ C, long sCbw, long sCh, int ldc,
    int K, int Ntiles)
{
  __shared__ __align__(16) u16 As[2][128 * 32];
  __shared__ __align__(16) u16 Bs[2][128 * 32];
  const int tid = threadIdx.x, lane = tid & 63, wid = tid >> 6;
  const int ln = lane & 15, quad = lane >> 4;
  const int blk = blockIdx.x & 127;
  const int rem = blockIdx.x >> 7;
  const int mt = rem / Ntiles, nt = rem % Ntiles;
  const int bw = blk >> 1, h = blk & 1;
  const u16* Ab = A + (size_t)bw * sAbw + (size_t)h * sAh + (size_t)mt * 128 * lda;
  const u16* Bp = B + (size_t)bw * sBbw + (size_t)h * sBh + (size_t)nt * 128 * ldb;
  u16*       Cp = C + (size_t)bw * sCbw + (size_t)h * sCh + (size_t)mt * 128 * ldc + nt * 128;
  const int srow = lane >> 2;
  const int skk  = (lane & 3) << 3;
  const int wm = (wid >> 1) << 6, wn = (wid & 1) << 6;

  f32x4 acc[4][4];
#pragma unroll
  for (int i = 0; i < 4; i++)
#pragma unroll
    for (int j = 0; j < 4; j++) acc[i][j] = (f32x4){0.f, 0.f, 0.f, 0.f};

  {
    const int kt2 = 0;
#pragma unroll
    for (int i = 0; i < 2; i++) {
      const int rr = i * 64 + wid * 16 + srow;
      GSTAGE(As[0], Ab, lda);
      GSTAGE(Bs[0], Bp, ldb);
    }
  }
  int cur = 0;
  for (int kt = 0; kt < K; kt += 32, cur ^= 1) {
    __syncthreads();
    if (kt + 32 < K) {
      const int kt2 = kt + 32;
#pragma unroll
      for (int i = 0; i < 2; i++) {
        const int rr = i * 64 + wid * 16 + srow;
        GSTAGE(As[cur ^ 1], Ab, lda);
        GSTAGE(Bs[cur ^ 1], Bp, ldb);
      }
    }
    short8 a[4], b[4];
#pragma unroll
    for (int i = 0; i < 4; i++) a[i] = *(const short8*)(As[cur] + (wm + i * 16 + ln) * 32 + quad * 8);
#pragma unroll
    for (int j = 0; j < 4; j++) b[j] = *(const short8*)(Bs[cur] + (wn + j * 16 + ln) * 32 + quad * 8);
#pragma unroll
    for (int i = 0; i < 4; i++)
#pragma unroll
      for (int j = 0; j < 4; j++)
        acc[i][j] = __builtin_amdgcn_mfma_f32_16x16x32_bf16(b[j], a[i], acc[i][j], 0, 0, 0);
  }

#pragma unroll
  for (int i = 0; i < 4; i++) {
    const int m = wm + i * 16 + ln;
#pragma unroll
    for (int j = 0; j < 4; j++) {
      const int n0 = wn + j * 16 + quad * 4;
      const f32x4 v = acc[i][j];
      ushort4 ob;
      ob.x = f2b(v[0]); ob.y = f2b(v[1]); ob.z = f2b(v[2]); ob.w = f2b(v[3]);
      *(ushort4*)(Cp + (size_t)m * ldc + n0) = ob;
    }
  }
}

// ---------------------------------------------------------------------------
// GEMM (N=256) with FUSED residual + LayerNorm epilogue.
// Block = 64 rows x 256 cols (4 waves side-by-side in N).
__global__ __launch_bounds__(256) void gemm_ln(
    const u16* __restrict__ A, const u16* __restrict__ BT,
    const float* __restrict__ bias, const float* __restrict__ resid,
    const float* __restrict__ g, const float* __restrict__ beta,
    float* __restrict__ yout, u16* __restrict__ ybout, int K)
{
  __shared__ __align__(16) u16 As[64 * 32];
  __shared__ __align__(16) u16 Bs[256 * 32];
  __shared__ float redS[4][64], redQ[4][64];
  const int tid = threadIdx.x, lane = tid & 63, wid = tid >> 6;
  const int ln = lane & 15, quad = lane >> 4;
  const long bm = (long)blockIdx.x * 64;
  const int wn = wid * 64;
  const u16* Ab = A + (size_t)bm * K;

  f32x4 acc[4][4];
#pragma unroll
  for (int i = 0; i < 4; i++)
#pragma unroll
    for (int j = 0; j < 4; j++) acc[i][j] = (f32x4){0.f, 0.f, 0.f, 0.f};

  for (int kt = 0; kt < K; kt += 32) {
    {                                       // A: 64x32 = 256 slots, 1/thread
      const int row = tid >> 2, c = tid & 3;
      __builtin_amdgcn_global_load_lds(
          (AS1C)(Ab + (size_t)row * K + kt + c * 8), (AS3P)(As + tid * 8), 16, 0, 0);
    }
#pragma unroll
    for (int p = 0; p < 4; p++) {           // B: 256x32 = 1024 slots
      const int s = p * 256 + tid;
      const int row = s >> 2, c = s & 3;
      __builtin_amdgcn_global_load_lds(
          (AS1C)(BT + (size_t)row * K + kt + c * 8), (AS3P)(Bs + s * 8), 16, 0, 0);
    }
    __syncthreads();
    short8 a[4], b[4];
#pragma unroll
    for (int i = 0; i < 4; i++) a[i] = *(const short8*)(As + (i * 16 + ln) * 32 + quad * 8);
#pragma unroll
    for (int j = 0; j < 4; j++) b[j] = *(const short8*)(Bs + (wn + j * 16 + ln) * 32 + quad * 8);
#pragma unroll
    for (int i = 0; i < 4; i++)
#pragma unroll
      for (int j = 0; j < 4; j++)
        acc[i][j] = __builtin_amdgcn_mfma_f32_16x16x32_bf16(b[j], a[i], acc[i][j], 0, 0, 0);
    __syncthreads();
  }

  // ---- epilogue: v = acc + bias + resid; LayerNorm over the 256-row ----
#pragma unroll
  for (int i = 0; i < 4; i++) {
    const long gm = bm + i * 16 + ln;
    float s = 0.f, q = 0.f;
#pragma unroll
    for (int j = 0; j < 4; j++) {
      const int n0 = wn + j * 16 + quad * 4;
      const float4 b4 = *(const float4*)(bias + n0);
      const float4 r4 = *(const float4*)(resid + (size_t)gm * 256 + n0);
      acc[i][j][0] += b4.x + r4.x;
      acc[i][j][1] += b4.y + r4.y;
      acc[i][j][2] += b4.z + r4.z;
      acc[i][j][3] += b4.w + r4.w;
#pragma unroll
      for (int r = 0; r < 4; r++) { s += acc[i][j][r]; q += acc[i][j][r] * acc[i][j][r]; }
    }
    s += __shfl_xor(s, 16); s += __shfl_xor(s, 32);
    q += __shfl_xor(q, 16); q += __shfl_xor(q, 32);
    if (quad == 0) { redS[wid][i * 16 + ln] = s; redQ[wid][i * 16 + ln] = q; }
  }
  __syncthreads();
#pragma unroll
  for (int i = 0; i < 4; i++) {
    const long gm = bm + i * 16 + ln;
    float s = 0.f, q = 0.f;
#pragma unroll
    for (int w = 0; w < 4; w++) { s += redS[w][i * 16 + ln]; q += redQ[w][i * 16 + ln]; }
    const float mu = s * (1.f / 256.f);
    const float inv = rsqrtf(q * (1.f / 256.f) - mu * mu + 1e-3f);
#pragma unroll
    for (int j = 0; j < 4; j++) {
      const int n0 = wn + j * 16 + quad * 4;
      const float4 gg = *(const float4*)(g + n0);
      const float4 bb = *(const float4*)(beta + n0);
      float o0 = (acc[i][j][0] - mu) * inv * gg.x + bb.x;
      float o1 = (acc[i][j][1] - mu) * inv * gg.y + bb.y;
      float o2 = (acc[i][j][2] - mu) * inv * gg.z + bb.z;
      float o3 = (acc[i][j][3] - mu) * inv * gg.w + bb.w;
      const size_t off = (size_t)gm * 256 + n0;
      if (yout) {
        float4 o4; o4.x = o0; o4.y = o1; o4.z = o2; o4.w = o3;
        *(float4*)(yout + off) = o4;
      }
      if (ybout) {
        ushort4 ob;
        ob.x = f2b(o0); ob.y = f2b(o1); ob.z = f2b(o2); ob.w = f2b(o3);
        *(ushort4*)(ybout + off) = ob;
      }
    }
  }
}

// ---------------------------------------------------------------------------
__global__ __launch_bounds__(256) void transpose_v(const u16* __restrict__ qkv,
                                                   u16* __restrict__ vt)
{
  __shared__ u16 tile[64][72];
  const int bid = blockIdx.x;                 // 128 * 8 * 4
  const int kt4 = bid & 3, tt = (bid >> 2) & 7, blk = bid >> 5;
  const int bw = blk >> 1, h = blk & 1;
  const int lk = threadIdx.x & 63, l0 = threadIdx.x >> 6;
#pragma unroll
  for (int i = 0; i < 16; i++) {
    const int lt = l0 + i * 4;
    tile[lt][lk] = qkv[(size_t)(bw * 512 + tt * 64 + lt) * 1536 + 1024 + h * 256 + kt4 * 64 + lk];
  }
  __syncthreads();
#pragma unroll
  for (int i = 0; i < 16; i++) {
    const int kk = l0 + i * 4;
    vt[((size_t)blk * 256 + kt4 * 64 + kk) * 512 + tt * 64 + lk] = tile[lk][kk];
  }
}

// ---------------------------------------------------------------------------
extern "C" void kernel_launch(void* const* d_in, const int* in_sizes, int n_in,
                              void* d_out, int out_size, void* d_ws, size_t ws_size,
                              hipStream_t stream) {
  (void)in_sizes; (void)n_in; (void)out_size; (void)ws_size;
  const float* x    = (const float*)d_in[0];
  const float* Wq   = (const float*)d_in[1];
  const float* bq   = (const float*)d_in[2];
  const float* Wk   = (const float*)d_in[3];
  const float* bk   = (const float*)d_in[4];
  const float* Wv   = (const float*)d_in[5];
  const float* bv   = (const float*)d_in[6];
  const float* Wo   = (const float*)d_in[7];
  const float* bo   = (const float*)d_in[8];
  const float* ln1g = (const float*)d_in[9];
  const float* ln1b = (const float*)d_in[10];
  const float* W1   = (const float*)d_in[11];
  const float* b1   = (const float*)d_in[12];
  const float* W2   = (const float*)d_in[13];
  const float* b2   = (const float*)d_in[14];
  const float* ln2g = (const float*)d_in[15];
  const float* ln2b = (const float*)d_in[16];
  float* out = (float*)d_out;

  char* ws = (char*)d_ws;
  u16*   WQKVT = (u16*)(ws + OFF_WQKVT);
  u16*   WOT   = (u16*)(ws + OFF_WOT);
  u16*   W1T   = (u16*)(ws + OFF_W1T);
  u16*   W2T   = (u16*)(ws + OFF_W2T);
  float* BQKV  = (float*)(ws + OFF_BQKV);
  u16*   XB    = (u16*)(ws + OFF_XB);
  u16*   QKV   = (u16*)(ws + OFF_QKV);
  float* Y     = (float*)(ws + OFF_Y);
  u16*   YB    = (u16*)(ws + OFF_YB);
  u16*   HB    = (u16*)(ws + OFF_HB);
  u16*   VT    = (u16*)(ws + OFF_VT);
  u16*   CTX   = (u16*)(ws + OFF_CTX);
  u16*   S     = (u16*)(ws + OFF_S);

  cast_x_kernel<<<8192, 256, 0, stream>>>(x, XB);
  prep_w_kernel<<<1024, 256, 0, stream>>>(Wq, Wk, Wv, Wo, W1, W2, bq, bk, bv,
                                          WQKVT, WOT, W1T, W2T, BQKV);
  // QKV projection: [32768,256] x [256,1536], BK=64
  gemm_bt<<<3072, 256, 0, stream>>>(XB, WQKVT, BQKV, nullptr, QKV,
                                    MTOK, 1536, 256, 0);
  transpose_v<<<4096, 256, 0, stream>>>(QKV, VT);
  // P = softmax(Q K^T / 16), fused: 128 batches x 8 m-tiles
  bgemm_qk<<<1024, 512, 0, stream>>>(QKV, S);
  // CTX = P V batched: M=512,N=256,K=512
  bgemm<<<1024, 256, 0, stream>>>(S,   524288, 262144, 512,
                                  VT,  262144, 131072, 512,
                                  CTX, 262144, 256, 512,
                                  512, 2);
  // attn-out projection + residual(x) + LN1 -> Y (f32) + YB (bf16)
  gemm_ln<<<512, 256, 0, stream>>>(CTX, WOT, bo, x, ln1g, ln1b, Y, YB, 512);
  // FF1 + ReLU: [32768,256] x [256,1024], BK=64
  gemm_bt<<<2048, 256, 0, stream>>>(YB, W1T, b1, nullptr, HB,
                                    MTOK, 1024, 256, 1);
  // FF2 + residual(Y) + LN2 -> out (f32)
  gemm_ln<<<512, 256, 0, stream>>>(HB, W2T, b2, Y, ln2g, ln2b, out, nullptr, 1024);
}

// Round 6
// 373.213 us; speedup vs baseline: 1.2721x; 1.1130x over previous
//
#include <hip/hip_runtime.h>

typedef unsigned short u16;
typedef short short8 __attribute__((ext_vector_type(8)));
typedef float f32x4 __attribute__((ext_vector_type(4)));

#define AS1C const __attribute__((address_space(1))) void*
#define AS3P __attribute__((address_space(3))) void*

// ---------- bf16 helpers ----------
__device__ __forceinline__ u16 f2b(float f) {
  unsigned u = __float_as_uint(f);
  return (u16)((u + 0x7fffu + ((u >> 16) & 1u)) >> 16);   // RNE
}
__device__ __forceinline__ float b2f(u16 h) {
  return __uint_as_float((unsigned)h << 16);
}

// ---------- problem constants ----------
#define BB 8
#define SS 4096
#define DD 256
#define MTOK (BB*SS)          // 32768 tokens

// ---------- workspace offsets (bytes) ----------
#define OFF_WQKVT  ((size_t)0)           // bf16 [1536][256]
#define OFF_WOT    ((size_t)786432)      // bf16 [256][512]
#define OFF_W1T    ((size_t)1048576)     // bf16 [1024][256]
#define OFF_W2T    ((size_t)1572864)     // bf16 [256][1024]
#define OFF_BQKV   ((size_t)2097152)     // f32  [1536]
#define OFF_XB     ((size_t)2103296)     // bf16 [32768][256]
#define OFF_QKV    ((size_t)18880512)    // bf16 [32768][1536] (V third unused)
#define OFF_YB     ((size_t)52434944)    // bf16 [32768][256]
#define OFF_HB     ((size_t)69212160)    // bf16 [32768][1024]
#define OFF_VT     ((size_t)119543808)   // bf16 [128][256][512] (dead before HB written)
#define OFF_CTX    ((size_t)153098240)   // bf16 [32768][512]
#define OFF_S      ((size_t)186652672)   // bf16 [128][512][512] (softmaxed P)

// ---------------------------------------------------------------------------
__global__ __launch_bounds__(256) void cast_x_kernel(const float* __restrict__ x,
                                                     u16* __restrict__ xb) {
  size_t i = ((size_t)blockIdx.x * 256 + threadIdx.x) * 4;
  float4 v = *(const float4*)(x + i);
  ushort4 o;
  o.x = f2b(v.x); o.y = f2b(v.y); o.z = f2b(v.z); o.w = f2b(v.w);
  *(ushort4*)(xb + i) = o;
}

// ---------------------------------------------------------------------------
__global__ __launch_bounds__(256) void prep_w_kernel(
    const float* __restrict__ Wq, const float* __restrict__ Wk, const float* __restrict__ Wv,
    const float* __restrict__ Wo, const float* __restrict__ W1, const float* __restrict__ W2,
    const float* __restrict__ bq, const float* __restrict__ bk, const float* __restrict__ bv,
    u16* __restrict__ wqkvt, u16* __restrict__ wot, u16* __restrict__ w1t,
    u16* __restrict__ w2t, float* __restrict__ bqkv)
{
  for (int i = blockIdx.x * 256 + threadIdx.x; i < 1050112; i += 1024 * 256) {
    if (i < 393216) {                       // WQKVT [1536][256]
      int n = i >> 8, d = i & 255;
      const float* W = (n < 512) ? Wq : (n < 1024) ? Wk : Wv;
      int nn = n & 511;
      wqkvt[i] = f2b(W[d * 512 + nn]);
    } else if (i < 524288) {                // WOT [256][512]
      int j = i - 393216;
      int dout = j >> 9, hk = j & 511;
      wot[j] = f2b(Wo[hk * 256 + dout]);
    } else if (i < 786432) {                // W1T [1024][256]
      int j = i - 524288;
      int f = j >> 8, d = j & 255;
      w1t[j] = f2b(W1[d * 1024 + f]);
    } else if (i < 1048576) {               // W2T [256][1024]
      int j = i - 786432;
      int d = j >> 10, f = j & 1023;
      w2t[j] = f2b(W2[f * 256 + d]);
    } else {                                // bias concat [1536]
      int n = i - 1048576;
      bqkv[n] = (n < 512) ? bq[n] : (n < 1024) ? bk[n - 512] : bv[n - 1024];
    }
  }
}

// ---------------------------------------------------------------------------
// B-resident streaming GEMM for K=256: C = A[M,256] * BT[N,256]^T + bias.
// Block = n-panel (128 cols) x m-chunk (512 rows = 8 m-iters of 64).
// Phase 0: stage B panel (64 KB) -> LDS -> 128 VGPRs of frags per lane.
// Phase 1: LDS becomes A double-buffer (2 x 32 KB); per m-iter one barrier,
// prefetch next A-tile, 64 MFMA/wave from registers+LDS-A only.
// XOR chunk swizzle (c = pc ^ (row&31)) applied on the global source side;
// read side compensates -> conflict-free ds_read_b128.
// V-panels (n >= vbase, QKV only) write transposed straight to VT.
// Grid: bid = pn*64 + mg  (64%8==0 -> A-chunk sharers land on one XCD).
__global__ __launch_bounds__(256) void gemm_nres(
    const u16* __restrict__ A, const u16* __restrict__ BT,
    const float* __restrict__ bias, u16* __restrict__ C,
    u16* __restrict__ vt, int N, int vbase, int relu)
{
  __shared__ __align__(16) u16 lds[32768];          // 64 KB
  const int tid = threadIdx.x, lane = tid & 63, wid = tid >> 6;
  const int ln = lane & 15, quad = lane >> 4;
  const int pn = blockIdx.x >> 6;                   // n-panel
  const int mg = blockIdx.x & 63;                   // m-chunk (512 rows)
  const int wm = (wid >> 1) << 5;                   // 0 / 32
  const int wn = (wid & 1) << 6;                    // 0 / 64
  const long mbase = (long)mg << 9;
  const int nb = pn << 7;
  const u16* Bp = BT + (size_t)nb * 256;
  const u16* Ap = A + (size_t)mbase * 256;

  // ---- phase 0: stage B panel 128x256 (4096 slots of 16B) ----
#pragma unroll
  for (int p = 0; p < 16; p++) {
    const int s = p * 256 + tid;
    const int row = s >> 5, pc = s & 31;
    const int c = pc ^ (row & 31);
    __builtin_amdgcn_global_load_lds(
        (AS1C)(Bp + (size_t)row * 256 + c * 8), (AS3P)(lds + s * 8), 16, 0, 0);
  }
  __syncthreads();
  short8 breg[4][8];                                // 128 VGPRs
#pragma unroll
  for (int j = 0; j < 4; j++) {
    const int row = wn + j * 16 + ln;
#pragma unroll
    for (int ks = 0; ks < 8; ks++)
      breg[j][ks] = *(const short8*)(lds + row * 256 + (((ks << 2) + quad) ^ (row & 31)) * 8);
  }
  __syncthreads();                                  // all B reads done before A overwrites

  // ---- A prologue: iter 0 -> buf 0 (2048 slots of 16B = 32 KB) ----
#pragma unroll
  for (int p = 0; p < 8; p++) {
    const int s = p * 256 + tid;
    const int row = s >> 5, pc = s & 31;
    const int c = pc ^ (row & 31);
    __builtin_amdgcn_global_load_lds(
        (AS1C)(Ap + (size_t)row * 256 + c * 8), (AS3P)(lds + s * 8), 16, 0, 0);
  }

  for (int it = 0; it < 8; it++) {
    const int cur = it & 1;
    const u16* Ab = lds + cur * 16384;
    __syncthreads();                                // drains buf-cur loads
    if (it + 1 < 8) {                               // prefetch next A-tile
      const u16* An = Ap + (size_t)(it + 1) * 64 * 256;
      u16* Ax = lds + (cur ^ 1) * 16384;
#pragma unroll
      for (int p = 0; p < 8; p++) {
        const int s = p * 256 + tid;
        const int row = s >> 5, pc = s & 31;
        const int c = pc ^ (row & 31);
        __builtin_amdgcn_global_load_lds(
            (AS1C)(An + (size_t)row * 256 + c * 8), (AS3P)(Ax + s * 8), 16, 0, 0);
      }
    }
    f32x4 acc[2][4];
#pragma unroll
    for (int i = 0; i < 2; i++)
#pragma unroll
      for (int j = 0; j < 4; j++) acc[i][j] = (f32x4){0.f, 0.f, 0.f, 0.f};
    const int r0 = wm + ln, r1 = wm + 16 + ln;
#pragma unroll
    for (int ks = 0; ks < 8; ks++) {
      const short8 a0 = *(const short8*)(Ab + r0 * 256 + (((ks << 2) + quad) ^ (r0 & 31)) * 8);
      const short8 a1 = *(const short8*)(Ab + r1 * 256 + (((ks << 2) + quad) ^ (r1 & 31)) * 8);
#pragma unroll
      for (int j = 0; j < 4; j++) {
        acc[0][j] = __builtin_amdgcn_mfma_f32_16x16x32_bf16(breg[j][ks], a0, acc[0][j], 0, 0, 0);
        acc[1][j] = __builtin_amdgcn_mfma_f32_16x16x32_bf16(breg[j][ks], a1, acc[1][j], 0, 0, 0);
      }
    }
    // ---- epilogue for this 64-row slab ----
    const long mrow0 = mbase + it * 64;
    if (nb < vbase) {
#pragma unroll
      for (int i = 0; i < 2; i++) {
        const long m = mrow0 + wm + i * 16 + ln;
#pragma unroll
        for (int j = 0; j < 4; j++) {
          const int n0 = nb + wn + j * 16 + quad * 4;
          f32x4 v = acc[i][j];
          const float4 b4 = *(const float4*)(bias + n0);
          v[0] += b4.x; v[1] += b4.y; v[2] += b4.z; v[3] += b4.w;
          if (relu) {
#pragma unroll
            for (int r = 0; r < 4; r++) v[r] = fmaxf(v[r], 0.f);
          }
          ushort4 ob;
          ob.x = f2b(v[0]); ob.y = f2b(v[1]); ob.z = f2b(v[2]); ob.w = f2b(v[3]);
          *(ushort4*)(C + (size_t)m * N + n0) = ob;
        }
      }
    } else {
      // V-panel: write transposed to VT[blk=bw*2+h][k][t]
#pragma unroll
      for (int i = 0; i < 2; i++) {
        const long m = mrow0 + wm + i * 16 + ln;
        const int bw = (int)(m >> 9), t = (int)(m & 511);
#pragma unroll
        for (int j = 0; j < 4; j++) {
          const int n0 = nb + wn + j * 16 + quad * 4;
          const int h = (n0 - vbase) >> 8, k0 = (n0 - vbase) & 255;
          u16* vp = vt + (size_t)(bw * 2 + h) * 131072 + (size_t)k0 * 512 + t;
          const float4 b4 = *(const float4*)(bias + n0);
          vp[0]    = f2b(acc[i][j][0] + b4.x);
          vp[512]  = f2b(acc[i][j][1] + b4.y);
          vp[1024] = f2b(acc[i][j][2] + b4.z);
          vp[1536] = f2b(acc[i][j][3] + b4.w);
        }
      }
    }
  }
}

// ---------------------------------------------------------------------------
// QK^T with FUSED softmax. One block = one (b,w,h) batch x 64 Q-rows.
// XCD swizzle: bat = bid & 127.
__global__ __launch_bounds__(512) void bgemm_qk(const u16* __restrict__ qkv,
                                                u16* __restrict__ S)
{
  __shared__ __align__(16) u16 As[64 * 32];
  __shared__ __align__(16) u16 Bs[512 * 32];
  __shared__ float red1[8][64], red2[8][64];
  const int tid = threadIdx.x, lane = tid & 63, wid = tid >> 6;
  const int ln = lane & 15, quad = lane >> 4;
  const int bat = blockIdx.x & 127, mt = blockIdx.x >> 7;
  const int bw = bat >> 1, h = bat & 1;
  const u16* Qb = qkv + (size_t)bw * 786432 + (size_t)h * 256 + (size_t)(mt * 64) * 1536;
  const u16* Kb = qkv + (size_t)bw * 786432 + 512 + (size_t)h * 256;
  u16* Sb = S + (size_t)bat * 262144 + (size_t)(mt * 64) * 512;
  const int wn = wid * 64;

  f32x4 acc[4][4];
#pragma unroll
  for (int i = 0; i < 4; i++)
#pragma unroll
    for (int j = 0; j < 4; j++) acc[i][j] = (f32x4){0.f, 0.f, 0.f, 0.f};

  for (int kt = 0; kt < 256; kt += 32) {
    if (tid < 256) {                        // Q tile: 64x32 = 256 slots
      const int row = tid >> 2, c = tid & 3;
      __builtin_amdgcn_global_load_lds(
          (AS1C)(Qb + (size_t)row * 1536 + kt + c * 8), (AS3P)(As + tid * 8), 16, 0, 0);
    }
#pragma unroll
    for (int p = 0; p < 4; p++) {           // K tile: 512x32 = 2048 slots
      const int s = p * 512 + tid;
      const int row = s >> 2, c = s & 3;
      __builtin_amdgcn_global_load_lds(
          (AS1C)(Kb + (size_t)row * 1536 + kt + c * 8), (AS3P)(Bs + s * 8), 16, 0, 0);
    }
    __syncthreads();
    short8 a[4], b[4];
#pragma unroll
    for (int i = 0; i < 4; i++) a[i] = *(const short8*)(As + (i * 16 + ln) * 32 + quad * 8);
#pragma unroll
    for (int j = 0; j < 4; j++) b[j] = *(const short8*)(Bs + (wn + j * 16 + ln) * 32 + quad * 8);
#pragma unroll
    for (int i = 0; i < 4; i++)
#pragma unroll
      for (int j = 0; j < 4; j++)
        acc[i][j] = __builtin_amdgcn_mfma_f32_16x16x32_bf16(b[j], a[i], acc[i][j], 0, 0, 0);
    __syncthreads();
  }

  float rowmax[4];
#pragma unroll
  for (int i = 0; i < 4; i++) {
    float m = -1e30f;
#pragma unroll
    for (int j = 0; j < 4; j++)
#pragma unroll
      for (int r = 0; r < 4; r++) m = fmaxf(m, acc[i][j][r]);
    m = fmaxf(m, __shfl_xor(m, 16));
    m = fmaxf(m, __shfl_xor(m, 32));
    if (quad == 0) red1[wid][i * 16 + ln] = m;
    rowmax[i] = m;
  }
  __syncthreads();
#pragma unroll
  for (int i = 0; i < 4; i++) {
    float m = -1e30f;
#pragma unroll
    for (int w = 0; w < 8; w++) m = fmaxf(m, red1[w][i * 16 + ln]);
    rowmax[i] = m;
  }
  float rowsum[4];
#pragma unroll
  for (int i = 0; i < 4; i++) {
    float s = 0.f;
#pragma unroll
    for (int j = 0; j < 4; j++)
#pragma unroll
      for (int r = 0; r < 4; r++) {
        const float e = __expf((acc[i][j][r] - rowmax[i]) * 0.0625f); // 1/sqrt(256)
        acc[i][j][r] = e; s += e;
      }
    s += __shfl_xor(s, 16);
    s += __shfl_xor(s, 32);
    if (quad == 0) red2[wid][i * 16 + ln] = s;
  }
  __syncthreads();
#pragma unroll
  for (int i = 0; i < 4; i++) {
    float s = 0.f;
#pragma unroll
    for (int w = 0; w < 8; w++) s += red2[w][i * 16 + ln];
    rowsum[i] = 1.f / s;
  }
#pragma unroll
  for (int i = 0; i < 4; i++) {
    const size_t roff = (size_t)(i * 16 + ln) * 512;
#pragma unroll
    for (int j = 0; j < 4; j++) {
      const int n0 = wn + j * 16 + quad * 4;
      ushort4 ob;
      ob.x = f2b(acc[i][j][0] * rowsum[i]);
      ob.y = f2b(acc[i][j][1] * rowsum[i]);
      ob.z = f2b(acc[i][j][2] * rowsum[i]);
      ob.w = f2b(acc[i][j][3] * rowsum[i]);
      *(ushort4*)(Sb + roff + n0) = ob;
    }
  }
}

// ---------------------------------------------------------------------------
// batched GEMM (P·V) over 128 blocks: C = A * B^T, bf16. dbuf BK=32.
#define GSTAGE(Sptr, Gptr, ld)                                                     \
  __builtin_amdgcn_global_load_lds(                                                \
      (AS1C)((Gptr) + (size_t)rr * (ld) + kt2 + skk),                              \
      (AS3P)((Sptr) + (size_t)(i * 64 + wid * 16) * 32), 16, 0, 0)

__global__ __launch_bounds__(256) void bgemm(
    const u16* __restrict__ A, long sAbw, long sAh, int lda,
    const u16* __restrict__ B, long sBbw, long sBh, int ldb,
    u16* __restrict__ C, long sCbw, long sCh, int ldc,
    int K, int Ntiles)
{
  __shared__ __align__(16) u16 As[2][128 * 32];
  __shared__ __align__(16) u16 Bs[2][128 * 32];
  const int tid = threadIdx.x, lane = tid & 63, wid = tid >> 6;
  const int ln = lane & 15, quad = lane >> 4;
  const int blk = blockIdx.x & 127;
  const int rem = blockIdx.x >> 7;
  const int mt = rem / Ntiles, nt = rem % Ntiles;
  const int bw = blk >> 1, h = blk & 1;
  const u16* Ab = A + (size_t)bw * sAbw + (size_t)h * sAh + (size_t)mt * 128 * lda;
  const u16* Bp = B + (size_t)bw * sBbw + (size_t)h * sBh + (size_t)nt * 128 * ldb;
  u16*       Cp = C + (size_t)bw * sCbw + (size_t)h * sCh + (size_t)mt * 128 * ldc + nt * 128;
  const int srow = lane >> 2;
  const int skk  = (lane & 3) << 3;
  const int wm = (wid >> 1) << 6, wn = (wid & 1) << 6;

  f32x4 acc[4][4];
#pragma unroll
  for (int i = 0; i < 4; i++)
#pragma unroll
    for (int j = 0; j < 4; j++) acc[i][j] = (f32x4){0.f, 0.f, 0.f, 0.f};

  {
    const int kt2 = 0;
#pragma unroll
    for (int i = 0; i < 2; i++) {
      const int rr = i * 64 + wid * 16 + srow;
      GSTAGE(As[0], Ab, lda);
      GSTAGE(Bs[0], Bp, ldb);
    }
  }
  int cur = 0;
  for (int kt = 0; kt < K; kt += 32, cur ^= 1) {
    __syncthreads();
    if (kt + 32 < K) {
      const int kt2 = kt + 32;
#pragma unroll
      for (int i = 0; i < 2; i++) {
        const int rr = i * 64 + wid * 16 + srow;
        GSTAGE(As[cur ^ 1], Ab, lda);
        GSTAGE(Bs[cur ^ 1], Bp, ldb);
      }
    }
    short8 a[4], b[4];
#pragma unroll
    for (int i = 0; i < 4; i++) a[i] = *(const short8*)(As[cur] + (wm + i * 16 + ln) * 32 + quad * 8);
#pragma unroll
    for (int j = 0; j < 4; j++) b[j] = *(const short8*)(Bs[cur] + (wn + j * 16 + ln) * 32 + quad * 8);
#pragma unroll
    for (int i = 0; i < 4; i++)
#pragma unroll
      for (int j = 0; j < 4; j++)
        acc[i][j] = __builtin_amdgcn_mfma_f32_16x16x32_bf16(b[j], a[i], acc[i][j], 0, 0, 0);
  }

#pragma unroll
  for (int i = 0; i < 4; i++) {
    const int m = wm + i * 16 + ln;
#pragma unroll
    for (int j = 0; j < 4; j++) {
      const int n0 = wn + j * 16 + quad * 4;
      const f32x4 v = acc[i][j];
      ushort4 ob;
      ob.x = f2b(v[0]); ob.y = f2b(v[1]); ob.z = f2b(v[2]); ob.w = f2b(v[3]);
      *(ushort4*)(Cp + (size_t)m * ldc + n0) = ob;
    }
  }
}

// ---------------------------------------------------------------------------
// GEMM (N=256) with FUSED residual(bf16) + LayerNorm epilogue.
// Block = 64 rows x 256 cols (4 waves side-by-side in N).
__global__ __launch_bounds__(256) void gemm_ln(
    const u16* __restrict__ A, const u16* __restrict__ BT,
    const float* __restrict__ bias, const u16* __restrict__ residb,
    const float* __restrict__ g, const float* __restrict__ beta,
    float* __restrict__ yout, u16* __restrict__ ybout, int K)
{
  __shared__ __align__(16) u16 As[64 * 32];
  __shared__ __align__(16) u16 Bs[256 * 32];
  __shared__ float redS[4][64], redQ[4][64];
  const int tid = threadIdx.x, lane = tid & 63, wid = tid >> 6;
  const int ln = lane & 15, quad = lane >> 4;
  const long bm = (long)blockIdx.x * 64;
  const int wn = wid * 64;
  const u16* Ab = A + (size_t)bm * K;

  f32x4 acc[4][4];
#pragma unroll
  for (int i = 0; i < 4; i++)
#pragma unroll
    for (int j = 0; j < 4; j++) acc[i][j] = (f32x4){0.f, 0.f, 0.f, 0.f};

  for (int kt = 0; kt < K; kt += 32) {
    {                                       // A: 64x32 = 256 slots, 1/thread
      const int row = tid >> 2, c = tid & 3;
      __builtin_amdgcn_global_load_lds(
          (AS1C)(Ab + (size_t)row * K + kt + c * 8), (AS3P)(As + tid * 8), 16, 0, 0);
    }
#pragma unroll
    for (int p = 0; p < 4; p++) {           // B: 256x32 = 1024 slots
      const int s = p * 256 + tid;
      const int row = s >> 2, c = s & 3;
      __builtin_amdgcn_global_load_lds(
          (AS1C)(BT + (size_t)row * K + kt + c * 8), (AS3P)(Bs + s * 8), 16, 0, 0);
    }
    __syncthreads();
    short8 a[4], b[4];
#pragma unroll
    for (int i = 0; i < 4; i++) a[i] = *(const short8*)(As + (i * 16 + ln) * 32 + quad * 8);
#pragma unroll
    for (int j = 0; j < 4; j++) b[j] = *(const short8*)(Bs + (wn + j * 16 + ln) * 32 + quad * 8);
#pragma unroll
    for (int i = 0; i < 4; i++)
#pragma unroll
      for (int j = 0; j < 4; j++)
        acc[i][j] = __builtin_amdgcn_mfma_f32_16x16x32_bf16(b[j], a[i], acc[i][j], 0, 0, 0);
    __syncthreads();
  }

  // ---- epilogue: v = acc + bias + resid; LayerNorm over the 256-row ----
#pragma unroll
  for (int i = 0; i < 4; i++) {
    const long gm = bm + i * 16 + ln;
    float s = 0.f, q = 0.f;
#pragma unroll
    for (int j = 0; j < 4; j++) {
      const int n0 = wn + j * 16 + quad * 4;
      const float4 b4 = *(const float4*)(bias + n0);
      const ushort4 r4 = *(const ushort4*)(residb + (size_t)gm * 256 + n0);
      acc[i][j][0] += b4.x + b2f(r4.x);
      acc[i][j][1] += b4.y + b2f(r4.y);
      acc[i][j][2] += b4.z + b2f(r4.z);
      acc[i][j][3] += b4.w + b2f(r4.w);
#pragma unroll
      for (int r = 0; r < 4; r++) { s += acc[i][j][r]; q += acc[i][j][r] * acc[i][j][r]; }
    }
    s += __shfl_xor(s, 16); s += __shfl_xor(s, 32);
    q += __shfl_xor(q, 16); q += __shfl_xor(q, 32);
    if (quad == 0) { redS[wid][i * 16 + ln] = s; redQ[wid][i * 16 + ln] = q; }
  }
  __syncthreads();
#pragma unroll
  for (int i = 0; i < 4; i++) {
    const long gm = bm + i * 16 + ln;
    float s = 0.f, q = 0.f;
#pragma unroll
    for (int w = 0; w < 4; w++) { s += redS[w][i * 16 + ln]; q += redQ[w][i * 16 + ln]; }
    const float mu = s * (1.f / 256.f);
    const float inv = rsqrtf(q * (1.f / 256.f) - mu * mu + 1e-3f);
#pragma unroll
    for (int j = 0; j < 4; j++) {
      const int n0 = wn + j * 16 + quad * 4;
      const float4 gg = *(const float4*)(g + n0);
      const float4 bb = *(const float4*)(beta + n0);
      float o0 = (acc[i][j][0] - mu) * inv * gg.x + bb.x;
      float o1 = (acc[i][j][1] - mu) * inv * gg.y + bb.y;
      float o2 = (acc[i][j][2] - mu) * inv * gg.z + bb.z;
      float o3 = (acc[i][j][3] - mu) * inv * gg.w + bb.w;
      const size_t off = (size_t)gm * 256 + n0;
      if (yout) {
        float4 o4; o4.x = o0; o4.y = o1; o4.z = o2; o4.w = o3;
        *(float4*)(yout + off) = o4;
      }
      if (ybout) {
        ushort4 ob;
        ob.x = f2b(o0); ob.y = f2b(o1); ob.z = f2b(o2); ob.w = f2b(o3);
        *(ushort4*)(ybout + off) = ob;
      }
    }
  }
}

// ---------------------------------------------------------------------------
extern "C" void kernel_launch(void* const* d_in, const int* in_sizes, int n_in,
                              void* d_out, int out_size, void* d_ws, size_t ws_size,
                              hipStream_t stream) {
  (void)in_sizes; (void)n_in; (void)out_size; (void)ws_size;
  const float* x    = (const float*)d_in[0];
  const float* Wq   = (const float*)d_in[1];
  const float* bq   = (const float*)d_in[2];
  const float* Wk   = (const float*)d_in[3];
  const float* bk   = (const float*)d_in[4];
  const float* Wv   = (const float*)d_in[5];
  const float* bv   = (const float*)d_in[6];
  const float* Wo   = (const float*)d_in[7];
  const float* bo   = (const float*)d_in[8];
  const float* ln1g = (const float*)d_in[9];
  const float* ln1b = (const float*)d_in[10];
  const float* W1   = (const float*)d_in[11];
  const float* b1   = (const float*)d_in[12];
  const float* W2   = (const float*)d_in[13];
  const float* b2   = (const float*)d_in[14];
  const float* ln2g = (const float*)d_in[15];
  const float* ln2b = (const float*)d_in[16];
  float* out = (float*)d_out;

  char* ws = (char*)d_ws;
  u16*   WQKVT = (u16*)(ws + OFF_WQKVT);
  u16*   WOT   = (u16*)(ws + OFF_WOT);
  u16*   W1T   = (u16*)(ws + OFF_W1T);
  u16*   W2T   = (u16*)(ws + OFF_W2T);
  float* BQKV  = (float*)(ws + OFF_BQKV);
  u16*   XB    = (u16*)(ws + OFF_XB);
  u16*   QKV   = (u16*)(ws + OFF_QKV);
  u16*   YB    = (u16*)(ws + OFF_YB);
  u16*   HB    = (u16*)(ws + OFF_HB);
  u16*   VT    = (u16*)(ws + OFF_VT);
  u16*   CTX   = (u16*)(ws + OFF_CTX);
  u16*   S     = (u16*)(ws + OFF_S);

  cast_x_kernel<<<8192, 256, 0, stream>>>(x, XB);
  prep_w_kernel<<<1024, 256, 0, stream>>>(Wq, Wk, Wv, Wo, W1, W2, bq, bk, bv,
                                          WQKVT, WOT, W1T, W2T, BQKV);
  // QKV projection (B-resident): Q,K -> QKV; V -> VT (fused transpose)
  gemm_nres<<<768, 256, 0, stream>>>(XB, WQKVT, BQKV, QKV, VT, 1536, 1024, 0);
  // P = softmax(Q K^T / 16), fused: 128 batches x 8 m-tiles
  bgemm_qk<<<1024, 512, 0, stream>>>(QKV, S);
  // CTX = P V batched: M=512,N=256,K=512
  bgemm<<<1024, 256, 0, stream>>>(S,   524288, 262144, 512,
                                  VT,  262144, 131072, 512,
                                  CTX, 262144, 256, 512,
                                  512, 2);
  // attn-out projection + residual(XB) + LN1 -> YB (bf16)
  gemm_ln<<<512, 256, 0, stream>>>(CTX, WOT, bo, XB, ln1g, ln1b, nullptr, YB, 512);
  // FF1 + ReLU (B-resident): [32768,256] x [256,1024]
  gemm_nres<<<512, 256, 0, stream>>>(YB, W1T, b1, HB, nullptr, 1024, 1 << 30, 1);
  // FF2 + residual(YB) + LN2 -> out (f32)
  gemm_ln<<<512, 256, 0, stream>>>(HB, W2T, b2, YB, ln2g, ln2b, out, nullptr, 1024);
}

// Round 7
// 368.521 us; speedup vs baseline: 1.2883x; 1.0127x over previous
//
#include <hip/hip_runtime.h>

typedef unsigned short u16;
typedef short short8 __attribute__((ext_vector_type(8)));
typedef float f32x4 __attribute__((ext_vector_type(4)));

#define AS1C const __attribute__((address_space(1))) void*
#define AS3P __attribute__((address_space(3))) void*

// ---------- bf16 helpers ----------
__device__ __forceinline__ u16 f2b(float f) {
  unsigned u = __float_as_uint(f);
  return (u16)((u + 0x7fffu + ((u >> 16) & 1u)) >> 16);   // RNE
}
__device__ __forceinline__ float b2f(u16 h) {
  return __uint_as_float((unsigned)h << 16);
}

// ---------- problem constants ----------
#define BB 8
#define SS 4096
#define DD 256
#define MTOK (BB*SS)          // 32768 tokens

// ---------- workspace offsets (bytes) ----------
#define OFF_WQKVT  ((size_t)0)           // bf16 [1536][256]
#define OFF_WOT    ((size_t)786432)      // bf16 [256][512]
#define OFF_W1T    ((size_t)1048576)     // bf16 [1024][256]
#define OFF_W2T    ((size_t)1572864)     // bf16 [256][1024]
#define OFF_BQKV   ((size_t)2097152)     // f32  [1536]
#define OFF_XB     ((size_t)2103296)     // bf16 [32768][256]
#define OFF_QKV    ((size_t)18880512)    // bf16 [32768][1536] (V third unused)
#define OFF_YB     ((size_t)52434944)    // bf16 [32768][256]
#define OFF_HB     ((size_t)69212160)    // bf16 [32768][1024]
#define OFF_VT     ((size_t)119543808)   // bf16 [128][256][512]
#define OFF_CTX    ((size_t)153098240)   // bf16 [32768][512]

// ---------------------------------------------------------------------------
__global__ __launch_bounds__(256) void cast_x_kernel(const float* __restrict__ x,
                                                     u16* __restrict__ xb) {
  size_t i = ((size_t)blockIdx.x * 256 + threadIdx.x) * 4;
  float4 v = *(const float4*)(x + i);
  ushort4 o;
  o.x = f2b(v.x); o.y = f2b(v.y); o.z = f2b(v.z); o.w = f2b(v.w);
  *(ushort4*)(xb + i) = o;
}

// ---------------------------------------------------------------------------
__global__ __launch_bounds__(256) void prep_w_kernel(
    const float* __restrict__ Wq, const float* __restrict__ Wk, const float* __restrict__ Wv,
    const float* __restrict__ Wo, const float* __restrict__ W1, const float* __restrict__ W2,
    const float* __restrict__ bq, const float* __restrict__ bk, const float* __restrict__ bv,
    u16* __restrict__ wqkvt, u16* __restrict__ wot, u16* __restrict__ w1t,
    u16* __restrict__ w2t, float* __restrict__ bqkv)
{
  for (int i = blockIdx.x * 256 + threadIdx.x; i < 1050112; i += 1024 * 256) {
    if (i < 393216) {                       // WQKVT [1536][256]
      int n = i >> 8, d = i & 255;
      const float* W = (n < 512) ? Wq : (n < 1024) ? Wk : Wv;
      int nn = n & 511;
      wqkvt[i] = f2b(W[d * 512 + nn]);
    } else if (i < 524288) {                // WOT [256][512]
      int j = i - 393216;
      int dout = j >> 9, hk = j & 511;
      wot[j] = f2b(Wo[hk * 256 + dout]);
    } else if (i < 786432) {                // W1T [1024][256]
      int j = i - 524288;
      int f = j >> 8, d = j & 255;
      w1t[j] = f2b(W1[d * 1024 + f]);
    } else if (i < 1048576) {               // W2T [256][1024]
      int j = i - 786432;
      int d = j >> 10, f = j & 1023;
      w2t[j] = f2b(W2[f * 256 + d]);
    } else {                                // bias concat [1536]
      int n = i - 1048576;
      bqkv[n] = (n < 512) ? bq[n] : (n < 1024) ? bk[n - 512] : bv[n - 1024];
    }
  }
}

// ---------------------------------------------------------------------------
// B-resident streaming GEMM for K=256, occupancy-optimized: 32 KB LDS.
// Block = n-panel (64 cols) x m-chunk (1024 rows = 32 iters of 32).
// Phase 0: B panel (64x256, 32 KB) -> LDS -> 64 VGPRs of frags/lane; then
// the same 32 KB LDS becomes the A double-buffer (2 x 16 KB, 32-row slabs).
// XOR chunk swizzle (c = pc ^ (row&31)) on global source side; conflict-free.
// V-panels (n >= vbase; QKV only) write transposed straight to VT.
// grid: bid = pn*32 + mg -> A-slab sharers (same mg) land on one XCD.
__global__ __launch_bounds__(256) void gemm_nres(
    const u16* __restrict__ A, const u16* __restrict__ BT,
    const float* __restrict__ bias, u16* __restrict__ C,
    u16* __restrict__ vt, int N, int vbase, int relu)
{
  __shared__ __align__(16) u16 lds[16384];          // 32 KB
  const int tid = threadIdx.x, lane = tid & 63, wid = tid >> 6;
  const int ln = lane & 15, quad = lane >> 4;
  const int pn = blockIdx.x >> 5;                   // n-panel (64 cols)
  const int mg = blockIdx.x & 31;                   // m-chunk (1024 rows)
  const int wno = (wid >> 1) << 5;                  // 0 / 32
  const int wmo = (wid & 1) << 4;                   // 0 / 16
  const long mbase = (long)mg << 10;
  const int nb = pn << 6;
  const u16* Bp = BT + (size_t)nb * 256;
  const u16* Ap = A + (size_t)mbase * 256;

  // ---- phase 0: stage B panel 64x256 (2048 slots of 16B) ----
#pragma unroll
  for (int p = 0; p < 8; p++) {
    const int s = p * 256 + tid;
    const int row = s >> 5, pc = s & 31;
    const int c = pc ^ (row & 31);
    __builtin_amdgcn_global_load_lds(
        (AS1C)(Bp + (size_t)row * 256 + c * 8), (AS3P)(lds + s * 8), 16, 0, 0);
  }
  __syncthreads();
  short8 breg[2][8];                                // 64 VGPRs
#pragma unroll
  for (int j = 0; j < 2; j++) {
    const int row = wno + j * 16 + ln;
#pragma unroll
    for (int ks = 0; ks < 8; ks++)
      breg[j][ks] = *(const short8*)(lds + row * 256 + (((ks << 2) + quad) ^ (row & 31)) * 8);
  }
  __syncthreads();                                  // B reads done before A overwrites

  // ---- A prologue: iter 0 -> buf 0 (1024 slots = 16 KB) ----
#pragma unroll
  for (int p = 0; p < 4; p++) {
    const int s = p * 256 + tid;
    const int row = s >> 5, pc = s & 31;
    const int c = pc ^ (row & 31);
    __builtin_amdgcn_global_load_lds(
        (AS1C)(Ap + (size_t)row * 256 + c * 8), (AS3P)(lds + s * 8), 16, 0, 0);
  }

  for (int it = 0; it < 32; it++) {
    const int cur = it & 1;
    const u16* Ab = lds + cur * 8192;
    __syncthreads();                                // drains buf-cur loads
    if (it + 1 < 32) {                              // prefetch next 32-row slab
      const u16* An = Ap + (size_t)(it + 1) * 32 * 256;
      u16* Ax = lds + (cur ^ 1) * 8192;
#pragma unroll
      for (int p = 0; p < 4; p++) {
        const int s = p * 256 + tid;
        const int row = s >> 5, pc = s & 31;
        const int c = pc ^ (row & 31);
        __builtin_amdgcn_global_load_lds(
            (AS1C)(An + (size_t)row * 256 + c * 8), (AS3P)(Ax + s * 8), 16, 0, 0);
      }
    }
    f32x4 acc[2];
    acc[0] = (f32x4){0.f, 0.f, 0.f, 0.f};
    acc[1] = (f32x4){0.f, 0.f, 0.f, 0.f};
    const int r0 = wmo + ln;
#pragma unroll
    for (int ks = 0; ks < 8; ks++) {
      const short8 a0 = *(const short8*)(Ab + r0 * 256 + (((ks << 2) + quad) ^ (r0 & 31)) * 8);
      acc[0] = __builtin_amdgcn_mfma_f32_16x16x32_bf16(breg[0][ks], a0, acc[0], 0, 0, 0);
      acc[1] = __builtin_amdgcn_mfma_f32_16x16x32_bf16(breg[1][ks], a0, acc[1], 0, 0, 0);
    }
    // ---- epilogue for this 32-row slab ----
    const long m = mbase + it * 32 + wmo + ln;
    if (nb < vbase) {
#pragma unroll
      for (int j = 0; j < 2; j++) {
        const int n0 = nb + wno + j * 16 + quad * 4;
        f32x4 v = acc[j];
        const float4 b4 = *(const float4*)(bias + n0);
        v[0] += b4.x; v[1] += b4.y; v[2] += b4.z; v[3] += b4.w;
        if (relu) {
#pragma unroll
          for (int r = 0; r < 4; r++) v[r] = fmaxf(v[r], 0.f);
        }
        ushort4 ob;
        ob.x = f2b(v[0]); ob.y = f2b(v[1]); ob.z = f2b(v[2]); ob.w = f2b(v[3]);
        *(ushort4*)(C + (size_t)m * N + n0) = ob;
      }
    } else {
      // V-panel: write transposed to VT[blk=bw*2+h][k][t]
      const int bw = (int)(m >> 9), t = (int)(m & 511);
#pragma unroll
      for (int j = 0; j < 2; j++) {
        const int n0 = nb + wno + j * 16 + quad * 4;
        const int rel = n0 - vbase;
        const int h = rel >> 8, k0 = rel & 255;
        u16* vp = vt + (size_t)(bw * 2 + h) * 131072 + (size_t)k0 * 512 + t;
        const float4 b4 = *(const float4*)(bias + n0);
        vp[0]    = f2b(acc[j][0] + b4.x);
        vp[512]  = f2b(acc[j][1] + b4.y);
        vp[1024] = f2b(acc[j][2] + b4.z);
        vp[1536] = f2b(acc[j][3] + b4.w);
      }
    }
  }
}

// ---------------------------------------------------------------------------
// FUSED attention: S = QK^T -> exact softmax (in regs) -> O = P V, no S in HBM.
// Block = one (b,w,h) batch x 64 Q-rows (mt). 512 threads = 8 waves.
// Phase 1: wave w computes S cols [64w,64w+64) (operand-swapped MFMA).
// Phase 2: 8 t-chunks of 64; chunk c's P-slice lives in wave c's registers ->
// wave c drops it (normalized, bf16) into LDS Pbuf; all waves stage the
// V^T chunk (XOR-swizzled global_load_lds) and accumulate O (waves split
// head-dim 256 into 8 x 32 cols).
// LDS union: phase1 [As 4K | Bs 32K | red 4K] vs phase2 [Pbuf 9K | Vc 32K].
// XCD swizzle: bat = bid & 127 (K/V L2 reuse within an XCD).
__global__ __launch_bounds__(512) void attn_fused(const u16* __restrict__ qkv,
                                                  const u16* __restrict__ vt,
                                                  u16* __restrict__ ctx)
{
  __shared__ __align__(16) u16 lds[20992];          // 41984 B
  const int tid = threadIdx.x, lane = tid & 63, wid = tid >> 6;
  const int ln = lane & 15, quad = lane >> 4;
  const int bat = blockIdx.x & 127, mt = blockIdx.x >> 7;
  const int bw = bat >> 1, h = bat & 1;
  const u16* Qb = qkv + (size_t)bw * 786432 + (size_t)h * 256 + (size_t)(mt * 64) * 1536;
  const u16* Kb = qkv + (size_t)bw * 786432 + 512 + (size_t)h * 256;
  const u16* Vb = vt + (size_t)bat * 131072;        // [256][512]
  const int wn = wid * 64;
  float* red1 = (float*)(lds + 18432);
  float* red2 = red1 + 512;

  // ---- phase 1: S = Q K^T ----
  f32x4 acc[4][4];
#pragma unroll
  for (int i = 0; i < 4; i++)
#pragma unroll
    for (int j = 0; j < 4; j++) acc[i][j] = (f32x4){0.f, 0.f, 0.f, 0.f};

  for (int kt = 0; kt < 256; kt += 32) {
    if (tid < 256) {                        // Q tile: 64x32 = 256 slots
      const int row = tid >> 2, c = tid & 3;
      __builtin_amdgcn_global_load_lds(
          (AS1C)(Qb + (size_t)row * 1536 + kt + c * 8), (AS3P)(lds + tid * 8), 16, 0, 0);
    }
#pragma unroll
    for (int p = 0; p < 4; p++) {           // K tile: 512x32 = 2048 slots
      const int s = p * 512 + tid;
      const int row = s >> 2, c = s & 3;
      __builtin_amdgcn_global_load_lds(
          (AS1C)(Kb + (size_t)row * 1536 + kt + c * 8), (AS3P)(lds + 2048 + s * 8), 16, 0, 0);
    }
    __syncthreads();
    short8 a[4], b[4];
#pragma unroll
    for (int i = 0; i < 4; i++) a[i] = *(const short8*)(lds + (i * 16 + ln) * 32 + quad * 8);
#pragma unroll
    for (int j = 0; j < 4; j++) b[j] = *(const short8*)(lds + 2048 + (wn + j * 16 + ln) * 32 + quad * 8);
#pragma unroll
    for (int i = 0; i < 4; i++)
#pragma unroll
      for (int j = 0; j < 4; j++)
        acc[i][j] = __builtin_amdgcn_mfma_f32_16x16x32_bf16(b[j], a[i], acc[i][j], 0, 0, 0);
    __syncthreads();
  }

  // ---- exact softmax over the 512-wide rows ----
  float rowmax[4], rowsum[4];
#pragma unroll
  for (int i = 0; i < 4; i++) {
    float m = -1e30f;
#pragma unroll
    for (int j = 0; j < 4; j++)
#pragma unroll
      for (int r = 0; r < 4; r++) m = fmaxf(m, acc[i][j][r]);
    m = fmaxf(m, __shfl_xor(m, 16));
    m = fmaxf(m, __shfl_xor(m, 32));
    if (quad == 0) red1[wid * 64 + i * 16 + ln] = m;
  }
  __syncthreads();
#pragma unroll
  for (int i = 0; i < 4; i++) {
    float m = -1e30f;
#pragma unroll
    for (int w = 0; w < 8; w++) m = fmaxf(m, red1[w * 64 + i * 16 + ln]);
    rowmax[i] = m;
  }
#pragma unroll
  for (int i = 0; i < 4; i++) {
    float s = 0.f;
#pragma unroll
    for (int j = 0; j < 4; j++)
#pragma unroll
      for (int r = 0; r < 4; r++) {
        const float e = __expf((acc[i][j][r] - rowmax[i]) * 0.0625f); // 1/sqrt(256)
        acc[i][j][r] = e; s += e;
      }
    s += __shfl_xor(s, 16);
    s += __shfl_xor(s, 32);
    if (quad == 0) red2[wid * 64 + i * 16 + ln] = s;
  }
  __syncthreads();
#pragma unroll
  for (int i = 0; i < 4; i++) {
    float s = 0.f;
#pragma unroll
    for (int w = 0; w < 8; w++) s += red2[w * 64 + i * 16 + ln];
    rowsum[i] = 1.f / s;
  }

  // ---- phase 2: O = P V ----
  u16* Pb = lds;                  // 64 x 72 bf16 (9216 B)
  u16* Vc = lds + 4608;           // 256 x 64 chunk, swizzled slots (32 KB)
  const int wno = wid * 32;
  f32x4 o[4][2];
#pragma unroll
  for (int i = 0; i < 4; i++) {
    o[i][0] = (f32x4){0.f, 0.f, 0.f, 0.f};
    o[i][1] = (f32x4){0.f, 0.f, 0.f, 0.f};
  }

  for (int c = 0; c < 8; c++) {
    __syncthreads();              // prev-chunk reads (and softmax reds) done
    if (wid == c) {               // owning wave drops its normalized P-slice
#pragma unroll
      for (int i = 0; i < 4; i++)
#pragma unroll
        for (int j = 0; j < 4; j++) {
          ushort4 pb;
          pb.x = f2b(acc[i][j][0] * rowsum[i]);
          pb.y = f2b(acc[i][j][1] * rowsum[i]);
          pb.z = f2b(acc[i][j][2] * rowsum[i]);
          pb.w = f2b(acc[i][j][3] * rowsum[i]);
          *(ushort4*)(Pb + (i * 16 + ln) * 72 + j * 16 + quad * 4) = pb;
        }
    }
#pragma unroll
    for (int p = 0; p < 4; p++) { // stage V^T chunk: 256 rows x 128 B
      const int s = p * 512 + tid;
      const int row = s >> 3, pc = s & 7;
      const int cc = pc ^ (row & 7);
      __builtin_amdgcn_global_load_lds(
          (AS1C)(Vb + (size_t)row * 512 + c * 64 + cc * 8), (AS3P)(Vc + s * 8), 16, 0, 0);
    }
    __syncthreads();              // Pbuf written + Vc arrived
#pragma unroll
    for (int ks = 0; ks < 2; ks++) {
      short8 ap[4];
#pragma unroll
      for (int i = 0; i < 4; i++)
        ap[i] = *(const short8*)(Pb + (i * 16 + ln) * 72 + ks * 32 + quad * 8);
#pragma unroll
      for (int j = 0; j < 2; j++) {
        const int kV = wno + j * 16 + ln;
        const short8 bv = *(const short8*)(Vc + kV * 64 + (((ks << 2) + quad) ^ (kV & 7)) * 8);
#pragma unroll
        for (int i = 0; i < 4; i++)
          o[i][j] = __builtin_amdgcn_mfma_f32_16x16x32_bf16(bv, ap[i], o[i][j], 0, 0, 0);
      }
    }
  }

  // ---- epilogue: write CTX rows [bw*512+mt*64 .. +64), cols h*256+wno+.. ----
  const size_t tokr0 = (size_t)bw * 512 + mt * 64;
#pragma unroll
  for (int i = 0; i < 4; i++) {
    const size_t row = tokr0 + i * 16 + ln;
#pragma unroll
    for (int j = 0; j < 2; j++) {
      const int col = h * 256 + wno + j * 16 + quad * 4;
      ushort4 ob;
      ob.x = f2b(o[i][j][0]); ob.y = f2b(o[i][j][1]);
      ob.z = f2b(o[i][j][2]); ob.w = f2b(o[i][j][3]);
      *(ushort4*)(ctx + row * 512 + col) = ob;
    }
  }
}

// ---------------------------------------------------------------------------
// GEMM (N=256) with FUSED residual(bf16) + LayerNorm epilogue.
// Block = 64 rows x 256 cols (4 waves side-by-side in N).
__global__ __launch_bounds__(256) void gemm_ln(
    const u16* __restrict__ A, const u16* __restrict__ BT,
    const float* __restrict__ bias, const u16* __restrict__ residb,
    const float* __restrict__ g, const float* __restrict__ beta,
    float* __restrict__ yout, u16* __restrict__ ybout, int K)
{
  __shared__ __align__(16) u16 As[64 * 32];
  __shared__ __align__(16) u16 Bs[256 * 32];
  __shared__ float redS[4][64], redQ[4][64];
  const int tid = threadIdx.x, lane = tid & 63, wid = tid >> 6;
  const int ln = lane & 15, quad = lane >> 4;
  const long bm = (long)blockIdx.x * 64;
  const int wn = wid * 64;
  const u16* Ab = A + (size_t)bm * K;

  f32x4 acc[4][4];
#pragma unroll
  for (int i = 0; i < 4; i++)
#pragma unroll
    for (int j = 0; j < 4; j++) acc[i][j] = (f32x4){0.f, 0.f, 0.f, 0.f};

  for (int kt = 0; kt < K; kt += 32) {
    {                                       // A: 64x32 = 256 slots, 1/thread
      const int row = tid >> 2, c = tid & 3;
      __builtin_amdgcn_global_load_lds(
          (AS1C)(Ab + (size_t)row * K + kt + c * 8), (AS3P)(As + tid * 8), 16, 0, 0);
    }
#pragma unroll
    for (int p = 0; p < 4; p++) {           // B: 256x32 = 1024 slots
      const int s = p * 256 + tid;
      const int row = s >> 2, c = s & 3;
      __builtin_amdgcn_global_load_lds(
          (AS1C)(BT + (size_t)row * K + kt + c * 8), (AS3P)(Bs + s * 8), 16, 0, 0);
    }
    __syncthreads();
    short8 a[4], b[4];
#pragma unroll
    for (int i = 0; i < 4; i++) a[i] = *(const short8*)(As + (i * 16 + ln) * 32 + quad * 8);
#pragma unroll
    for (int j = 0; j < 4; j++) b[j] = *(const short8*)(Bs + (wn + j * 16 + ln) * 32 + quad * 8);
#pragma unroll
    for (int i = 0; i < 4; i++)
#pragma unroll
      for (int j = 0; j < 4; j++)
        acc[i][j] = __builtin_amdgcn_mfma_f32_16x16x32_bf16(b[j], a[i], acc[i][j], 0, 0, 0);
    __syncthreads();
  }

  // ---- epilogue: v = acc + bias + resid; LayerNorm over the 256-row ----
#pragma unroll
  for (int i = 0; i < 4; i++) {
    const long gm = bm + i * 16 + ln;
    float s = 0.f, q = 0.f;
#pragma unroll
    for (int j = 0; j < 4; j++) {
      const int n0 = wn + j * 16 + quad * 4;
      const float4 b4 = *(const float4*)(bias + n0);
      const ushort4 r4 = *(const ushort4*)(residb + (size_t)gm * 256 + n0);
      acc[i][j][0] += b4.x + b2f(r4.x);
      acc[i][j][1] += b4.y + b2f(r4.y);
      acc[i][j][2] += b4.z + b2f(r4.z);
      acc[i][j][3] += b4.w + b2f(r4.w);
#pragma unroll
      for (int r = 0; r < 4; r++) { s += acc[i][j][r]; q += acc[i][j][r] * acc[i][j][r]; }
    }
    s += __shfl_xor(s, 16); s += __shfl_xor(s, 32);
    q += __shfl_xor(q, 16); q += __shfl_xor(q, 32);
    if (quad == 0) { redS[wid][i * 16 + ln] = s; redQ[wid][i * 16 + ln] = q; }
  }
  __syncthreads();
#pragma unroll
  for (int i = 0; i < 4; i++) {
    const long gm = bm + i * 16 + ln;
    float s = 0.f, q = 0.f;
#pragma unroll
    for (int w = 0; w < 4; w++) { s += redS[w][i * 16 + ln]; q += redQ[w][i * 16 + ln]; }
    const float mu = s * (1.f / 256.f);
    const float inv = rsqrtf(q * (1.f / 256.f) - mu * mu + 1e-3f);
#pragma unroll
    for (int j = 0; j < 4; j++) {
      const int n0 = wn + j * 16 + quad * 4;
      const float4 gg = *(const float4*)(g + n0);
      const float4 bb = *(const float4*)(beta + n0);
      float o0 = (acc[i][j][0] - mu) * inv * gg.x + bb.x;
      float o1 = (acc[i][j][1] - mu) * inv * gg.y + bb.y;
      float o2 = (acc[i][j][2] - mu) * inv * gg.z + bb.z;
      float o3 = (acc[i][j][3] - mu) * inv * gg.w + bb.w;
      const size_t off = (size_t)gm * 256 + n0;
      if (yout) {
        float4 o4; o4.x = o0; o4.y = o1; o4.z = o2; o4.w = o3;
        *(float4*)(yout + off) = o4;
      }
      if (ybout) {
        ushort4 ob;
        ob.x = f2b(o0); ob.y = f2b(o1); ob.z = f2b(o2); ob.w = f2b(o3);
        *(ushort4*)(ybout + off) = ob;
      }
    }
  }
}

// ---------------------------------------------------------------------------
extern "C" void kernel_launch(void* const* d_in, const int* in_sizes, int n_in,
                              void* d_out, int out_size, void* d_ws, size_t ws_size,
                              hipStream_t stream) {
  (void)in_sizes; (void)n_in; (void)out_size; (void)ws_size;
  const float* x    = (const float*)d_in[0];
  const float* Wq   = (const float*)d_in[1];
  const float* bq   = (const float*)d_in[2];
  const float* Wk   = (const float*)d_in[3];
  const float* bk   = (const float*)d_in[4];
  const float* Wv   = (const float*)d_in[5];
  const float* bv   = (const float*)d_in[6];
  const float* Wo   = (const float*)d_in[7];
  const float* bo   = (const float*)d_in[8];
  const float* ln1g = (const float*)d_in[9];
  const float* ln1b = (const float*)d_in[10];
  const float* W1   = (const float*)d_in[11];
  const float* b1   = (const float*)d_in[12];
  const float* W2   = (const float*)d_in[13];
  const float* b2   = (const float*)d_in[14];
  const float* ln2g = (const float*)d_in[15];
  const float* ln2b = (const float*)d_in[16];
  float* out = (float*)d_out;

  char* ws = (char*)d_ws;
  u16*   WQKVT = (u16*)(ws + OFF_WQKVT);
  u16*   WOT   = (u16*)(ws + OFF_WOT);
  u16*   W1T   = (u16*)(ws + OFF_W1T);
  u16*   W2T   = (u16*)(ws + OFF_W2T);
  float* BQKV  = (float*)(ws + OFF_BQKV);
  u16*   XB    = (u16*)(ws + OFF_XB);
  u16*   QKV   = (u16*)(ws + OFF_QKV);
  u16*   YB    = (u16*)(ws + OFF_YB);
  u16*   HB    = (u16*)(ws + OFF_HB);
  u16*   VT    = (u16*)(ws + OFF_VT);
  u16*   CTX   = (u16*)(ws + OFF_CTX);

  cast_x_kernel<<<8192, 256, 0, stream>>>(x, XB);
  prep_w_kernel<<<1024, 256, 0, stream>>>(Wq, Wk, Wv, Wo, W1, W2, bq, bk, bv,
                                          WQKVT, WOT, W1T, W2T, BQKV);
  // QKV projection (B-resident, 32 KB LDS): Q,K -> QKV; V -> VT (fused T)
  gemm_nres<<<768, 256, 0, stream>>>(XB, WQKVT, BQKV, QKV, VT, 1536, 1024, 0);
  // Fused attention: QK^T + softmax + PV -> CTX (no S in HBM)
  attn_fused<<<1024, 512, 0, stream>>>(QKV, VT, CTX);
  // attn-out projection + residual(XB) + LN1 -> YB (bf16)
  gemm_ln<<<512, 256, 0, stream>>>(CTX, WOT, bo, XB, ln1g, ln1b, nullptr, YB, 512);
  // FF1 + ReLU (B-resident): [32768,256] x [256,1024]
  gemm_nres<<<512, 256, 0, stream>>>(YB, W1T, b1, HB, nullptr, 1024, 1 << 30, 1);
  // FF2 + residual(YB) + LN2 -> out (f32)
  gemm_ln<<<512, 256, 0, stream>>>(HB, W2T, b2, YB, ln2g, ln2b, out, nullptr, 1024);
}